// Round 1
// baseline (1317.408 us; speedup 1.0000x reference)
//
#include <hip/hip_runtime.h>
#include <hip/hip_bf16.h>
#include <cstddef>

#define NEG_SLOPE 0.2f

// ---------------- CSR build ----------------

__global__ void hist_k(const int* __restrict__ dst, int* __restrict__ count, int E) {
    int i = blockIdx.x * 256 + threadIdx.x;
    if (i < E) atomicAdd(&count[dst[i]], 1);
}

__global__ void scan_local_k(const int* __restrict__ count, int* __restrict__ row_start,
                             int* __restrict__ bsums, int N) {
    __shared__ int tmp[1024];
    int tid = threadIdx.x;
    int i = blockIdx.x * 1024 + tid;
    int v = (i < N) ? count[i] : 0;
    tmp[tid] = v;
    __syncthreads();
    for (int off = 1; off < 1024; off <<= 1) {
        int t = tmp[tid];
        int add = (tid >= off) ? tmp[tid - off] : 0;
        __syncthreads();
        tmp[tid] = t + add;
        __syncthreads();
    }
    if (i < N) row_start[i] = tmp[tid] - v;   // exclusive
    if (tid == 1023) bsums[blockIdx.x] = tmp[1023];
}

__global__ void scan_sums_k(int* __restrict__ bsums, int nb,
                            int* __restrict__ row_start, int N, int E) {
    __shared__ int tmp[1024];
    int tid = threadIdx.x;
    int v = (tid < nb) ? bsums[tid] : 0;
    tmp[tid] = v;
    __syncthreads();
    for (int off = 1; off < 1024; off <<= 1) {
        int t = tmp[tid];
        int add = (tid >= off) ? tmp[tid - off] : 0;
        __syncthreads();
        tmp[tid] = t + add;
        __syncthreads();
    }
    if (tid < nb) bsums[tid] = tmp[tid] - v;  // exclusive
    if (tid == 0) row_start[N] = E;
}

__global__ void scan_add_k(int* __restrict__ row_start, int* __restrict__ cursor,
                           const int* __restrict__ bsums, int N) {
    int i = blockIdx.x * 1024 + threadIdx.x;
    if (i < N) {
        int v = row_start[i] + bsums[blockIdx.x];
        row_start[i] = v;
        cursor[i] = v;
    }
}

__global__ void scatter_k(const int* __restrict__ src, const int* __restrict__ dst,
                          int* __restrict__ cursor, int* __restrict__ csr, int E) {
    int i = blockIdx.x * 256 + threadIdx.x;
    if (i < E) {
        int d = dst[i];
        int pos = atomicAdd(&cursor[d], 1);
        csr[pos] = src[i];
    }
}

// ---------------- SGEMM (fp32, LDS-tiled, 4x4 per thread) ----------------
// C[M,Nc] = A[M,K] @ B[K,Nc]; K % 32 == 0, Nc % 64 == 0.

#define BM 64
#define BN 64
#define BKT 32

__global__ __launch_bounds__(256) void sgemm_k(const float* __restrict__ A,
                                               const float* __restrict__ B,
                                               float* __restrict__ C,
                                               int M, int Nc, int K) {
    __shared__ __align__(16) float As[BKT][BM + 4];  // +4 keeps float4 alignment, breaks conflicts
    __shared__ __align__(16) float Bs[BKT][BN];
    int bm = blockIdx.x * BM;
    int bn = blockIdx.y * BN;
    int t = threadIdx.x;
    int tc = t & 15;
    int tr = t >> 4;
    float acc[4][4] = {};

    for (int k0 = 0; k0 < K; k0 += BKT) {
        // A tile 64x32: each thread 2x float4, stored transposed As[k][m]
        {
            int row = t >> 3;            // 0..31
            int kk = (t & 7) << 2;       // 0,4..28
#pragma unroll
            for (int p = 0; p < 2; ++p) {
                int r = row + p * 32;
                int gr = bm + r;
                float4 v = make_float4(0.f, 0.f, 0.f, 0.f);
                if (gr < M) v = *(const float4*)(A + (size_t)gr * K + k0 + kk);
                As[kk + 0][r] = v.x; As[kk + 1][r] = v.y;
                As[kk + 2][r] = v.z; As[kk + 3][r] = v.w;
            }
        }
        // B tile 32x64
        {
            int bk = t >> 4;             // 0..15
            int cc = (t & 15) << 2;
#pragma unroll
            for (int p = 0; p < 2; ++p) {
                int k = bk + p * 16;
                *(float4*)(&Bs[k][cc]) = *(const float4*)(B + (size_t)(k0 + k) * Nc + bn + cc);
            }
        }
        __syncthreads();
#pragma unroll
        for (int kk2 = 0; kk2 < BKT; ++kk2) {
            float4 a4 = *(const float4*)(&As[kk2][tr << 2]);
            float4 b4 = *(const float4*)(&Bs[kk2][tc << 2]);
            float av[4] = {a4.x, a4.y, a4.z, a4.w};
            float bv[4] = {b4.x, b4.y, b4.z, b4.w};
#pragma unroll
            for (int i = 0; i < 4; ++i)
#pragma unroll
                for (int j = 0; j < 4; ++j)
                    acc[i][j] = fmaf(av[i], bv[j], acc[i][j]);
        }
        __syncthreads();
    }
#pragma unroll
    for (int i = 0; i < 4; ++i) {
        int gr = bm + (tr << 2) + i;
        if (gr < M) {
            float4 v = make_float4(acc[i][0], acc[i][1], acc[i][2], acc[i][3]);
            *(float4*)(C + (size_t)gr * Nc + bn + (tc << 2)) = v;
        }
    }
}

// ---------------- attention scores: alpha_s/alpha_d per (node, head) ----------------

template <int C>
__global__ void alpha_k(const float* __restrict__ h, const float* __restrict__ a_s,
                        const float* __restrict__ a_d, float* __restrict__ os,
                        float* __restrict__ od, int NH) {
    int i = blockIdx.x * 256 + threadIdx.x;  // i = n*8 + head
    if (i >= NH) return;
    int hh = i & 7;
    const float* hp = h + (size_t)i * C;
    float s = 0.f, d = 0.f;
#pragma unroll
    for (int c = 0; c < C; ++c) {
        float v = hp[c];
        s = fmaf(v, a_s[hh * C + c], s);
        d = fmaf(v, a_d[hh * C + c], d);
    }
    os[i] = s;
    od[i] = d;
}

// ---------------- layer 1 aggregation: one 64-lane wave per dst node ----------------
// lane l -> (head = l>>3, ch = l&7); h1 layout [n][h*8+c] = [n][l]

__global__ __launch_bounds__(64) void aggregate1_k(
    const float* __restrict__ h1, const float* __restrict__ as,
    const float* __restrict__ ad, const int* __restrict__ row_start,
    const int* __restrict__ csr, const float* __restrict__ b1,
    float* __restrict__ h1o, int N) {
    int n = blockIdx.x;
    int l = threadIdx.x;
    int h = l >> 3;
    float adv = ad[n * 8 + h];
    // self loop
    float e0 = as[n * 8 + h] + adv;
    e0 = e0 > 0.f ? e0 : NEG_SLOPE * e0;
    float ex0 = __expf(e0);
    float denom = ex0;
    float acc = ex0 * h1[(size_t)n * 64 + l];
    int start = row_start[n], end = row_start[n + 1];
    for (int e = start; e < end; ++e) {
        int s = csr[e];
        float ee = as[s * 8 + h] + adv;
        ee = ee > 0.f ? ee : NEG_SLOPE * ee;
        float ex = __expf(ee);
        denom += ex;
        acc = fmaf(ex, h1[(size_t)s * 64 + l], acc);
    }
    float v = acc / denom + b1[l];
    h1o[(size_t)n * 64 + l] = v > 0.f ? v : expm1f(v);  // ELU
}

// ---------------- layer 2 aggregation: 128 threads per dst node ----------------
// thread t -> (head = t>>4, ch = t&15); h2 layout [n][h*16+c] = [n][t]

__global__ __launch_bounds__(128) void aggregate2_k(
    const float* __restrict__ h2, const float* __restrict__ as,
    const float* __restrict__ ad, const int* __restrict__ row_start,
    const int* __restrict__ csr, const float* __restrict__ b2,
    float* __restrict__ out, int N) {
    int n = blockIdx.x;
    int t = threadIdx.x;
    int h = t >> 4, c = t & 15;
    float adv = ad[n * 8 + h];
    float e0 = as[n * 8 + h] + adv;
    e0 = e0 > 0.f ? e0 : NEG_SLOPE * e0;
    float ex0 = __expf(e0);
    float denom = ex0;
    float acc = ex0 * h2[(size_t)n * 128 + t];
    int start = row_start[n], end = row_start[n + 1];
    for (int e = start; e < end; ++e) {
        int s = csr[e];
        float ee = as[s * 8 + h] + adv;
        ee = ee > 0.f ? ee : NEG_SLOPE * ee;
        float ex = __expf(ee);
        denom += ex;
        acc = fmaf(ex, h2[(size_t)s * 128 + t], acc);
    }
    __shared__ float red[128];
    red[t] = acc / denom;
    __syncthreads();
    if (t < 16) {
        float sum = 0.f;
#pragma unroll
        for (int hh = 0; hh < 8; ++hh) sum += red[hh * 16 + t];
        out[(size_t)n * 16 + t] = sum * 0.125f + b2[t];  // mean over heads + bias
    }
}

// ---------------- launch ----------------

extern "C" void kernel_launch(void* const* d_in, const int* in_sizes, int n_in,
                              void* d_out, int out_size, void* d_ws, size_t ws_size,
                              hipStream_t stream) {
    (void)n_in; (void)out_size; (void)ws_size;
    const float* x      = (const float*)d_in[0];
    const int*   ei     = (const int*)d_in[1];
    const float* W1     = (const float*)d_in[2];
    const float* a_src1 = (const float*)d_in[3];
    const float* a_dst1 = (const float*)d_in[4];
    const float* b1     = (const float*)d_in[5];
    const float* W2     = (const float*)d_in[6];
    const float* a_src2 = (const float*)d_in[7];
    const float* a_dst2 = (const float*)d_in[8];
    const float* b2     = (const float*)d_in[9];

    int N = in_sizes[0] / 512;
    int E = in_sizes[1] / 2;
    const int* src = ei;
    const int* dst = ei + E;

    char* ws = (char*)d_ws;
    size_t off = 0;
    auto alloc = [&](size_t bytes) -> void* {
        void* p = ws + off;
        off = (off + bytes + 255) & ~(size_t)255;
        return p;
    };
    float* h1   = (float*)alloc((size_t)N * 64 * 4);
    float* h1o  = (float*)alloc((size_t)N * 64 * 4);
    float* h2   = (float*)alloc((size_t)N * 128 * 4);
    float* as1  = (float*)alloc((size_t)N * 8 * 4);
    float* ad1  = (float*)alloc((size_t)N * 8 * 4);
    float* as2  = (float*)alloc((size_t)N * 8 * 4);
    float* ad2  = (float*)alloc((size_t)N * 8 * 4);
    int* row_start = (int*)alloc((size_t)(N + 1) * 4);
    int* cursor    = (int*)alloc((size_t)N * 4);
    int* count     = (int*)alloc((size_t)N * 4);
    int* bsums     = (int*)alloc(1024 * 4);
    int* csr       = (int*)alloc((size_t)E * 4);

    // --- CSR build (shared by both layers; self-loops folded analytically) ---
    hipMemsetAsync(count, 0, (size_t)N * 4, stream);
    hipMemsetAsync(bsums, 0, 1024 * 4, stream);
    hist_k<<<(E + 255) / 256, 256, 0, stream>>>(dst, count, E);
    int nb = (N + 1023) / 1024;
    scan_local_k<<<nb, 1024, 0, stream>>>(count, row_start, bsums, N);
    scan_sums_k<<<1, 1024, 0, stream>>>(bsums, nb, row_start, N, E);
    scan_add_k<<<nb, 1024, 0, stream>>>(row_start, cursor, bsums, N);
    scatter_k<<<(E + 255) / 256, 256, 0, stream>>>(src, dst, cursor, csr, E);

    // --- layer 1 ---
    dim3 g1((N + BM - 1) / BM, 1);
    sgemm_k<<<g1, 256, 0, stream>>>(x, W1, h1, N, 64, 512);
    alpha_k<8><<<(N * 8 + 255) / 256, 256, 0, stream>>>(h1, a_src1, a_dst1, as1, ad1, N * 8);
    aggregate1_k<<<N, 64, 0, stream>>>(h1, as1, ad1, row_start, csr, b1, h1o, N);

    // --- layer 2 ---
    dim3 g2((N + BM - 1) / BM, 2);
    sgemm_k<<<g2, 256, 0, stream>>>(h1o, W2, h2, N, 128, 64);
    alpha_k<16><<<(N * 8 + 255) / 256, 256, 0, stream>>>(h2, a_src2, a_dst2, as2, ad2, N * 8);
    aggregate2_k<<<N, 128, 0, stream>>>(h2, as2, ad2, row_start, csr, b2, (float*)d_out, N);
}

// Round 2
// 1033.996 us; speedup vs baseline: 1.2741x; 1.2741x over previous
//
#include <hip/hip_runtime.h>
#include <hip/hip_bf16.h>
#include <hip/hip_fp16.h>
#include <cstddef>

#define NEG_SLOPE 0.2f

// ---------------- CSR build ----------------

__global__ void hist_k(const int* __restrict__ dst, int* __restrict__ count, int E) {
    int i = blockIdx.x * 256 + threadIdx.x;
    if (i < E) atomicAdd(&count[dst[i]], 1);
}

__global__ void scan_local_k(const int* __restrict__ count, int* __restrict__ row_start,
                             int* __restrict__ bsums, int N) {
    __shared__ int tmp[1024];
    int tid = threadIdx.x;
    int i = blockIdx.x * 1024 + tid;
    int v = (i < N) ? count[i] : 0;
    tmp[tid] = v;
    __syncthreads();
    for (int off = 1; off < 1024; off <<= 1) {
        int t = tmp[tid];
        int add = (tid >= off) ? tmp[tid - off] : 0;
        __syncthreads();
        tmp[tid] = t + add;
        __syncthreads();
    }
    if (i < N) row_start[i] = tmp[tid] - v;   // exclusive
    if (tid == 1023) bsums[blockIdx.x] = tmp[1023];
}

__global__ void scan_sums_k(int* __restrict__ bsums, int nb,
                            int* __restrict__ row_start, int N, int E) {
    __shared__ int tmp[1024];
    int tid = threadIdx.x;
    int v = (tid < nb) ? bsums[tid] : 0;
    tmp[tid] = v;
    __syncthreads();
    for (int off = 1; off < 1024; off <<= 1) {
        int t = tmp[tid];
        int add = (tid >= off) ? tmp[tid - off] : 0;
        __syncthreads();
        tmp[tid] = t + add;
        __syncthreads();
    }
    if (tid < nb) bsums[tid] = tmp[tid] - v;  // exclusive
    if (tid == 0) row_start[N] = E;
}

__global__ void scan_add_k(int* __restrict__ row_start, int* __restrict__ cursor,
                           const int* __restrict__ bsums, int N) {
    int i = blockIdx.x * 1024 + threadIdx.x;
    if (i < N) {
        int v = row_start[i] + bsums[blockIdx.x];
        row_start[i] = v;
        cursor[i] = v;
    }
}

__global__ void scatter_k(const int* __restrict__ src, const int* __restrict__ dst,
                          int* __restrict__ cursor, int* __restrict__ csr, int E) {
    int i = blockIdx.x * 256 + threadIdx.x;
    if (i < E) {
        int d = dst[i];
        int pos = atomicAdd(&cursor[d], 1);
        csr[pos] = src[i];
    }
}

// ---------------- SGEMM (fp32 accumulate, fp16 output, LDS-tiled, 4x4/thread) ----
// C[M,Nc] = A[M,K] @ B[K,Nc]; K % 32 == 0, Nc % 64 == 0. C stored as __half.

#define BM 64
#define BN 64
#define BKT 32

__global__ __launch_bounds__(256) void sgemm_k(const float* __restrict__ A,
                                               const float* __restrict__ B,
                                               __half* __restrict__ C,
                                               int M, int Nc, int K) {
    __shared__ __align__(16) float As[BKT][BM + 4];
    __shared__ __align__(16) float Bs[BKT][BN];
    int bm = blockIdx.x * BM;
    int bn = blockIdx.y * BN;
    int t = threadIdx.x;
    int tc = t & 15;
    int tr = t >> 4;
    float acc[4][4] = {};

    for (int k0 = 0; k0 < K; k0 += BKT) {
        {
            int row = t >> 3;
            int kk = (t & 7) << 2;
#pragma unroll
            for (int p = 0; p < 2; ++p) {
                int r = row + p * 32;
                int gr = bm + r;
                float4 v = make_float4(0.f, 0.f, 0.f, 0.f);
                if (gr < M) v = *(const float4*)(A + (size_t)gr * K + k0 + kk);
                As[kk + 0][r] = v.x; As[kk + 1][r] = v.y;
                As[kk + 2][r] = v.z; As[kk + 3][r] = v.w;
            }
        }
        {
            int bk = t >> 4;
            int cc = (t & 15) << 2;
#pragma unroll
            for (int p = 0; p < 2; ++p) {
                int k = bk + p * 16;
                *(float4*)(&Bs[k][cc]) = *(const float4*)(B + (size_t)(k0 + k) * Nc + bn + cc);
            }
        }
        __syncthreads();
#pragma unroll
        for (int kk2 = 0; kk2 < BKT; ++kk2) {
            float4 a4 = *(const float4*)(&As[kk2][tr << 2]);
            float4 b4 = *(const float4*)(&Bs[kk2][tc << 2]);
            float av[4] = {a4.x, a4.y, a4.z, a4.w};
            float bv[4] = {b4.x, b4.y, b4.z, b4.w};
#pragma unroll
            for (int i = 0; i < 4; ++i)
#pragma unroll
                for (int j = 0; j < 4; ++j)
                    acc[i][j] = fmaf(av[i], bv[j], acc[i][j]);
        }
        __syncthreads();
    }
#pragma unroll
    for (int i = 0; i < 4; ++i) {
        int gr = bm + (tr << 2) + i;
        if (gr < M) {
            ushort4 p;
            p.x = __half_as_ushort(__float2half(acc[i][0]));
            p.y = __half_as_ushort(__float2half(acc[i][1]));
            p.z = __half_as_ushort(__float2half(acc[i][2]));
            p.w = __half_as_ushort(__float2half(acc[i][3]));
            *(ushort4*)(C + (size_t)gr * Nc + bn + (tc << 2)) = p;
        }
    }
}

// ---------------- attention scores: alpha_s/alpha_d per (node, head) ----------------

template <int C>
__global__ void alpha_k(const __half* __restrict__ h, const float* __restrict__ a_s,
                        const float* __restrict__ a_d, float* __restrict__ os,
                        float* __restrict__ od, int NH) {
    int i = blockIdx.x * 256 + threadIdx.x;  // i = n*8 + head
    if (i >= NH) return;
    int hh = i & 7;
    const __half* hp = h + (size_t)i * C;
    float s = 0.f, d = 0.f;
#pragma unroll
    for (int c = 0; c < C; ++c) {
        float v = __half2float(hp[c]);
        s = fmaf(v, a_s[hh * C + c], s);
        d = fmaf(v, a_d[hh * C + c], d);
    }
    os[i] = s;
    od[i] = d;
}

// ---------------- layer 1 aggregation: one 64-lane wave per dst node ----------------
// lane l -> (head = l>>3, ch = l&7); h1 layout [n][h*8+c] = [n][l], fp16

__global__ __launch_bounds__(64) void aggregate1_k(
    const __half* __restrict__ h1, const float* __restrict__ as,
    const float* __restrict__ ad, const int* __restrict__ row_start,
    const int* __restrict__ csr, const float* __restrict__ b1,
    float* __restrict__ h1o, int N) {
    int n = blockIdx.x;
    int l = threadIdx.x;
    int h = l >> 3;
    float adv = ad[n * 8 + h];
    float e0 = as[n * 8 + h] + adv;
    e0 = e0 > 0.f ? e0 : NEG_SLOPE * e0;
    float ex0 = __expf(e0);
    float denom = ex0;
    float acc = ex0 * __half2float(h1[(size_t)n * 64 + l]);
    int e = row_start[n], end = row_start[n + 1];
    for (; e + 2 <= end; e += 2) {
        int s0 = csr[e], s1 = csr[e + 1];
        float a0 = as[s0 * 8 + h];
        float a1 = as[s1 * 8 + h];
        float v0 = __half2float(h1[(size_t)s0 * 64 + l]);
        float v1 = __half2float(h1[(size_t)s1 * 64 + l]);
        float t0 = a0 + adv; t0 = t0 > 0.f ? t0 : NEG_SLOPE * t0;
        float t1 = a1 + adv; t1 = t1 > 0.f ? t1 : NEG_SLOPE * t1;
        float x0 = __expf(t0), x1 = __expf(t1);
        denom += x0 + x1;
        acc = fmaf(x0, v0, acc);
        acc = fmaf(x1, v1, acc);
    }
    if (e < end) {
        int s0 = csr[e];
        float t0 = as[s0 * 8 + h] + adv; t0 = t0 > 0.f ? t0 : NEG_SLOPE * t0;
        float x0 = __expf(t0);
        denom += x0;
        acc = fmaf(x0, __half2float(h1[(size_t)s0 * 64 + l]), acc);
    }
    float v = acc / denom + b1[l];
    h1o[(size_t)n * 64 + l] = v > 0.f ? v : expm1f(v);  // ELU
}

// ---------------- layer 2 aggregation: one wave per dst node, half2 lanes ---------
// lane l -> (head = l>>3, cpair = l&7 -> channels 2*cpair, 2*cpair+1); h2 fp16

__global__ __launch_bounds__(64) void aggregate2_k(
    const __half* __restrict__ h2, const float* __restrict__ as,
    const float* __restrict__ ad, const int* __restrict__ row_start,
    const int* __restrict__ csr, const float* __restrict__ b2,
    float* __restrict__ out, int N) {
    int n = blockIdx.x;
    int l = threadIdx.x;
    int h = l >> 3;
    const __half2* H = (const __half2*)h2;  // [n][64] half2
    float adv = ad[n * 8 + h];
    float e0 = as[n * 8 + h] + adv;
    e0 = e0 > 0.f ? e0 : NEG_SLOPE * e0;
    float ex0 = __expf(e0);
    float denom = ex0;
    float2 self = __half22float2(H[(size_t)n * 64 + l]);
    float accx = ex0 * self.x, accy = ex0 * self.y;
    int e = row_start[n], end = row_start[n + 1];
    for (; e + 2 <= end; e += 2) {
        int s0 = csr[e], s1 = csr[e + 1];
        float a0 = as[s0 * 8 + h];
        float a1 = as[s1 * 8 + h];
        float2 v0 = __half22float2(H[(size_t)s0 * 64 + l]);
        float2 v1 = __half22float2(H[(size_t)s1 * 64 + l]);
        float t0 = a0 + adv; t0 = t0 > 0.f ? t0 : NEG_SLOPE * t0;
        float t1 = a1 + adv; t1 = t1 > 0.f ? t1 : NEG_SLOPE * t1;
        float x0 = __expf(t0), x1 = __expf(t1);
        denom += x0 + x1;
        accx = fmaf(x0, v0.x, accx); accy = fmaf(x0, v0.y, accy);
        accx = fmaf(x1, v1.x, accx); accy = fmaf(x1, v1.y, accy);
    }
    if (e < end) {
        int s0 = csr[e];
        float t0 = as[s0 * 8 + h] + adv; t0 = t0 > 0.f ? t0 : NEG_SLOPE * t0;
        float x0 = __expf(t0);
        float2 v0 = __half22float2(H[(size_t)s0 * 64 + l]);
        denom += x0;
        accx = fmaf(x0, v0.x, accx); accy = fmaf(x0, v0.y, accy);
    }
    float rx = accx / denom, ry = accy / denom;
    // sum over heads: butterfly across lane bits 3,4,5
#pragma unroll
    for (int m = 8; m <= 32; m <<= 1) {
        rx += __shfl_xor(rx, m, 64);
        ry += __shfl_xor(ry, m, 64);
    }
    if (l < 8) {
        int c0 = l * 2;
        float2 o;
        o.x = rx * 0.125f + b2[c0];
        o.y = ry * 0.125f + b2[c0 + 1];
        *(float2*)(out + (size_t)n * 16 + c0) = o;
    }
}

// ---------------- launch ----------------

extern "C" void kernel_launch(void* const* d_in, const int* in_sizes, int n_in,
                              void* d_out, int out_size, void* d_ws, size_t ws_size,
                              hipStream_t stream) {
    (void)n_in; (void)out_size; (void)ws_size;
    const float* x      = (const float*)d_in[0];
    const int*   ei     = (const int*)d_in[1];
    const float* W1     = (const float*)d_in[2];
    const float* a_src1 = (const float*)d_in[3];
    const float* a_dst1 = (const float*)d_in[4];
    const float* b1     = (const float*)d_in[5];
    const float* W2     = (const float*)d_in[6];
    const float* a_src2 = (const float*)d_in[7];
    const float* a_dst2 = (const float*)d_in[8];
    const float* b2     = (const float*)d_in[9];

    int N = in_sizes[0] / 512;
    int E = in_sizes[1] / 2;
    const int* src = ei;
    const int* dst = ei + E;

    char* ws = (char*)d_ws;
    size_t off = 0;
    auto alloc = [&](size_t bytes) -> void* {
        void* p = ws + off;
        off = (off + bytes + 255) & ~(size_t)255;
        return p;
    };
    __half* h1  = (__half*)alloc((size_t)N * 64 * 2);
    float*  h1o = (float*)alloc((size_t)N * 64 * 4);
    __half* h2  = (__half*)alloc((size_t)N * 128 * 2);
    float* as1  = (float*)alloc((size_t)N * 8 * 4);
    float* ad1  = (float*)alloc((size_t)N * 8 * 4);
    float* as2  = (float*)alloc((size_t)N * 8 * 4);
    float* ad2  = (float*)alloc((size_t)N * 8 * 4);
    int* row_start = (int*)alloc((size_t)(N + 1) * 4);
    int* cursor    = (int*)alloc((size_t)N * 4);
    int* count     = (int*)alloc((size_t)N * 4);
    int* bsums     = (int*)alloc(1024 * 4);
    int* csr       = (int*)alloc((size_t)E * 4);

    // --- CSR build (shared by both layers; self-loops folded analytically) ---
    hipMemsetAsync(count, 0, (size_t)N * 4, stream);
    hipMemsetAsync(bsums, 0, 1024 * 4, stream);
    hist_k<<<(E + 255) / 256, 256, 0, stream>>>(dst, count, E);
    int nb = (N + 1023) / 1024;
    scan_local_k<<<nb, 1024, 0, stream>>>(count, row_start, bsums, N);
    scan_sums_k<<<1, 1024, 0, stream>>>(bsums, nb, row_start, N, E);
    scan_add_k<<<nb, 1024, 0, stream>>>(row_start, cursor, bsums, N);
    scatter_k<<<(E + 255) / 256, 256, 0, stream>>>(src, dst, cursor, csr, E);

    // --- layer 1 ---
    dim3 g1((N + BM - 1) / BM, 1);
    sgemm_k<<<g1, 256, 0, stream>>>(x, W1, h1, N, 64, 512);
    alpha_k<8><<<(N * 8 + 255) / 256, 256, 0, stream>>>(h1, a_src1, a_dst1, as1, ad1, N * 8);
    aggregate1_k<<<N, 64, 0, stream>>>(h1, as1, ad1, row_start, csr, b1, h1o, N);

    // --- layer 2 ---
    dim3 g2((N + BM - 1) / BM, 2);
    sgemm_k<<<g2, 256, 0, stream>>>(h1o, W2, h2, N, 128, 64);
    alpha_k<16><<<(N * 8 + 255) / 256, 256, 0, stream>>>(h2, a_src2, a_dst2, as2, ad2, N * 8);
    aggregate2_k<<<N, 64, 0, stream>>>(h2, as2, ad2, row_start, csr, b2, (float*)d_out, N);
}

// Round 3
// 748.138 us; speedup vs baseline: 1.7609x; 1.3821x over previous
//
#include <hip/hip_runtime.h>
#include <hip/hip_bf16.h>
#include <hip/hip_fp16.h>
#include <cstddef>

#define NEG_SLOPE 0.2f

// ================= bucketed CSR build =================
// Bucket = 512 consecutive dst nodes. NB = ceil(N/512) (== 196 for N=100000, must be <= 256).
// part[] holds (src << 9) | (dst & 511) packed per edge, grouped by bucket.

__global__ __launch_bounds__(256) void bucket_hist_k(const int* __restrict__ dst, int E,
                                                     int* __restrict__ bhist, int NB) {
    __shared__ int lh[256];
    for (int t = threadIdx.x; t < 256; t += 256) lh[t] = 0;
    __syncthreads();
    int per = (E + gridDim.x - 1) / gridDim.x;
    int s = blockIdx.x * per;
    int e = min(s + per, E);
    for (int i = s + threadIdx.x; i < e; i += 256) atomicAdd(&lh[dst[i] >> 9], 1);
    __syncthreads();
    for (int t = threadIdx.x; t < NB; t += 256)
        if (lh[t]) atomicAdd(&bhist[t], lh[t]);
}

__global__ __launch_bounds__(256) void bucket_scan_k(const int* __restrict__ bhist, int NB,
                                                     int* __restrict__ bbase, int* __restrict__ cursor,
                                                     int* __restrict__ row_start, int N, int E) {
    __shared__ int tmp[256];
    int tid = threadIdx.x;
    int v = (tid < NB) ? bhist[tid] : 0;
    tmp[tid] = v;
    __syncthreads();
    for (int d = 1; d < 256; d <<= 1) {
        int t = tmp[tid];
        int a = (tid >= d) ? tmp[tid - d] : 0;
        __syncthreads();
        tmp[tid] = t + a;
        __syncthreads();
    }
    if (tid < NB) {
        int b = tmp[tid] - v;  // exclusive
        bbase[tid] = b;
        cursor[tid] = b;
    }
    if (tid == 0) {
        bbase[NB] = E;
        row_start[N] = E;
    }
}

__global__ __launch_bounds__(256) void partition_k(const int* __restrict__ src,
                                                   const int* __restrict__ dst, int E,
                                                   int* __restrict__ cursor,
                                                   unsigned int* __restrict__ part, int NB) {
    __shared__ int lh[256];
    __shared__ int lbase[256];
    for (int t = threadIdx.x; t < 256; t += 256) lh[t] = 0;
    __syncthreads();
    int per = (E + gridDim.x - 1) / gridDim.x;
    int s = blockIdx.x * per;
    int e = min(s + per, E);
    for (int i = s + threadIdx.x; i < e; i += 256) atomicAdd(&lh[dst[i] >> 9], 1);
    __syncthreads();
    for (int t = threadIdx.x; t < NB; t += 256) {
        int c = lh[t];
        lbase[t] = c ? atomicAdd(&cursor[t], c) : 0;
        lh[t] = 0;  // becomes local cursor
    }
    __syncthreads();
    for (int i = s + threadIdx.x; i < e; i += 256) {
        int d = dst[i];
        int b = d >> 9;
        int lo = atomicAdd(&lh[b], 1);
        part[lbase[b] + lo] = ((unsigned)src[i] << 9) | (unsigned)(d & 511);
    }
}

// One workgroup per bucket: per-node counts + scan in LDS -> row_start; then scatter
// src ids into the bucket's contiguous csr window (L2-resident, ~64 KB).
__global__ __launch_bounds__(512) void bucket_build_k(const unsigned int* __restrict__ part,
                                                      const int* __restrict__ bbase,
                                                      int* __restrict__ row_start,
                                                      int* __restrict__ csr, int N) {
    __shared__ int cnt[512];
    __shared__ int cur[512];
    int b = blockIdx.x, tid = threadIdx.x;
    int n0 = b << 9;
    int s = bbase[b], e2 = bbase[b + 1];
    cnt[tid] = 0;
    __syncthreads();
    for (int i = s + tid; i < e2; i += 512) atomicAdd(&cnt[part[i] & 511], 1);
    __syncthreads();
    int v = cnt[tid];
    for (int d = 1; d < 512; d <<= 1) {  // inclusive scan, in place
        int t = cnt[tid];
        int a = (tid >= d) ? cnt[tid - d] : 0;
        __syncthreads();
        cnt[tid] = t + a;
        __syncthreads();
    }
    int excl = cnt[tid] - v;
    if (n0 + tid < N) row_start[n0 + tid] = s + excl;
    cur[tid] = excl;
    __syncthreads();
    for (int i = s + tid; i < e2; i += 512) {
        unsigned u = part[i];
        int p = atomicAdd(&cur[u & 511], 1);
        csr[s + p] = (int)(u >> 9);
    }
}

// ---------------- SGEMM (fp32 accumulate, fp16 output, LDS-tiled, 4x4/thread) ----
// C[M,Nc] = A[M,K] @ B[K,Nc]; K % 32 == 0, Nc % 64 == 0. C stored as __half.

#define BM 64
#define BN 64
#define BKT 32

__global__ __launch_bounds__(256) void sgemm_k(const float* __restrict__ A,
                                               const float* __restrict__ B,
                                               __half* __restrict__ C,
                                               int M, int Nc, int K) {
    __shared__ __align__(16) float As[BKT][BM + 4];
    __shared__ __align__(16) float Bs[BKT][BN];
    int bm = blockIdx.x * BM;
    int bn = blockIdx.y * BN;
    int t = threadIdx.x;
    int tc = t & 15;
    int tr = t >> 4;
    float acc[4][4] = {};

    for (int k0 = 0; k0 < K; k0 += BKT) {
        {
            int row = t >> 3;
            int kk = (t & 7) << 2;
#pragma unroll
            for (int p = 0; p < 2; ++p) {
                int r = row + p * 32;
                int gr = bm + r;
                float4 v = make_float4(0.f, 0.f, 0.f, 0.f);
                if (gr < M) v = *(const float4*)(A + (size_t)gr * K + k0 + kk);
                As[kk + 0][r] = v.x; As[kk + 1][r] = v.y;
                As[kk + 2][r] = v.z; As[kk + 3][r] = v.w;
            }
        }
        {
            int bk = t >> 4;
            int cc = (t & 15) << 2;
#pragma unroll
            for (int p = 0; p < 2; ++p) {
                int k = bk + p * 16;
                *(float4*)(&Bs[k][cc]) = *(const float4*)(B + (size_t)(k0 + k) * Nc + bn + cc);
            }
        }
        __syncthreads();
#pragma unroll
        for (int kk2 = 0; kk2 < BKT; ++kk2) {
            float4 a4 = *(const float4*)(&As[kk2][tr << 2]);
            float4 b4 = *(const float4*)(&Bs[kk2][tc << 2]);
            float av[4] = {a4.x, a4.y, a4.z, a4.w};
            float bv[4] = {b4.x, b4.y, b4.z, b4.w};
#pragma unroll
            for (int i = 0; i < 4; ++i)
#pragma unroll
                for (int j = 0; j < 4; ++j)
                    acc[i][j] = fmaf(av[i], bv[j], acc[i][j]);
        }
        __syncthreads();
    }
#pragma unroll
    for (int i = 0; i < 4; ++i) {
        int gr = bm + (tr << 2) + i;
        if (gr < M) {
            ushort4 p;
            p.x = __half_as_ushort(__float2half(acc[i][0]));
            p.y = __half_as_ushort(__float2half(acc[i][1]));
            p.z = __half_as_ushort(__float2half(acc[i][2]));
            p.w = __half_as_ushort(__float2half(acc[i][3]));
            *(ushort4*)(C + (size_t)gr * Nc + bn + (tc << 2)) = p;
        }
    }
}

// ---------------- attention scores: alpha_s/alpha_d per (node, head) ----------------

template <int C>
__global__ void alpha_k(const __half* __restrict__ h, const float* __restrict__ a_s,
                        const float* __restrict__ a_d, float* __restrict__ os,
                        float* __restrict__ od, int NH) {
    int i = blockIdx.x * 256 + threadIdx.x;  // i = n*8 + head
    if (i >= NH) return;
    int hh = i & 7;
    const __half* hp = h + (size_t)i * C;
    float s = 0.f, d = 0.f;
#pragma unroll
    for (int c = 0; c < C; ++c) {
        float v = __half2float(hp[c]);
        s = fmaf(v, a_s[hh * C + c], s);
        d = fmaf(v, a_d[hh * C + c], d);
    }
    os[i] = s;
    od[i] = d;
}

// ---------------- layer 1 aggregation: one 64-lane wave per dst node ----------------
// lane l -> (head = l>>3, ch = l&7); h1 layout [n][h*8+c] = [n][l], fp16

__global__ __launch_bounds__(64) void aggregate1_k(
    const __half* __restrict__ h1, const float* __restrict__ as,
    const float* __restrict__ ad, const int* __restrict__ row_start,
    const int* __restrict__ csr, const float* __restrict__ b1,
    float* __restrict__ h1o, int N) {
    int n = blockIdx.x;
    int l = threadIdx.x;
    int h = l >> 3;
    float adv = ad[n * 8 + h];
    float e0 = as[n * 8 + h] + adv;
    e0 = e0 > 0.f ? e0 : NEG_SLOPE * e0;
    float ex0 = __expf(e0);
    float denom = ex0;
    float acc = ex0 * __half2float(h1[(size_t)n * 64 + l]);
    int e = row_start[n], end = row_start[n + 1];
    for (; e + 2 <= end; e += 2) {
        int s0 = csr[e], s1 = csr[e + 1];
        float a0 = as[s0 * 8 + h];
        float a1 = as[s1 * 8 + h];
        float v0 = __half2float(h1[(size_t)s0 * 64 + l]);
        float v1 = __half2float(h1[(size_t)s1 * 64 + l]);
        float t0 = a0 + adv; t0 = t0 > 0.f ? t0 : NEG_SLOPE * t0;
        float t1 = a1 + adv; t1 = t1 > 0.f ? t1 : NEG_SLOPE * t1;
        float x0 = __expf(t0), x1 = __expf(t1);
        denom += x0 + x1;
        acc = fmaf(x0, v0, acc);
        acc = fmaf(x1, v1, acc);
    }
    if (e < end) {
        int s0 = csr[e];
        float t0 = as[s0 * 8 + h] + adv; t0 = t0 > 0.f ? t0 : NEG_SLOPE * t0;
        float x0 = __expf(t0);
        denom += x0;
        acc = fmaf(x0, __half2float(h1[(size_t)s0 * 64 + l]), acc);
    }
    float v = acc / denom + b1[l];
    h1o[(size_t)n * 64 + l] = v > 0.f ? v : expm1f(v);  // ELU
}

// ---------------- layer 2 aggregation: one wave per dst node, half2 lanes ---------
// lane l -> (head = l>>3, cpair = l&7 -> channels 2*cpair, 2*cpair+1); h2 fp16

__global__ __launch_bounds__(64) void aggregate2_k(
    const __half* __restrict__ h2, const float* __restrict__ as,
    const float* __restrict__ ad, const int* __restrict__ row_start,
    const int* __restrict__ csr, const float* __restrict__ b2,
    float* __restrict__ out, int N) {
    int n = blockIdx.x;
    int l = threadIdx.x;
    int h = l >> 3;
    const __half2* H = (const __half2*)h2;  // [n][64] half2
    float adv = ad[n * 8 + h];
    float e0 = as[n * 8 + h] + adv;
    e0 = e0 > 0.f ? e0 : NEG_SLOPE * e0;
    float ex0 = __expf(e0);
    float denom = ex0;
    float2 self = __half22float2(H[(size_t)n * 64 + l]);
    float accx = ex0 * self.x, accy = ex0 * self.y;
    int e = row_start[n], end = row_start[n + 1];
    for (; e + 2 <= end; e += 2) {
        int s0 = csr[e], s1 = csr[e + 1];
        float a0 = as[s0 * 8 + h];
        float a1 = as[s1 * 8 + h];
        float2 v0 = __half22float2(H[(size_t)s0 * 64 + l]);
        float2 v1 = __half22float2(H[(size_t)s1 * 64 + l]);
        float t0 = a0 + adv; t0 = t0 > 0.f ? t0 : NEG_SLOPE * t0;
        float t1 = a1 + adv; t1 = t1 > 0.f ? t1 : NEG_SLOPE * t1;
        float x0 = __expf(t0), x1 = __expf(t1);
        denom += x0 + x1;
        accx = fmaf(x0, v0.x, accx); accy = fmaf(x0, v0.y, accy);
        accx = fmaf(x1, v1.x, accx); accy = fmaf(x1, v1.y, accy);
    }
    if (e < end) {
        int s0 = csr[e];
        float t0 = as[s0 * 8 + h] + adv; t0 = t0 > 0.f ? t0 : NEG_SLOPE * t0;
        float x0 = __expf(t0);
        float2 v0 = __half22float2(H[(size_t)s0 * 64 + l]);
        denom += x0;
        accx = fmaf(x0, v0.x, accx); accy = fmaf(x0, v0.y, accy);
    }
    float rx = accx / denom, ry = accy / denom;
#pragma unroll
    for (int m = 8; m <= 32; m <<= 1) {
        rx += __shfl_xor(rx, m, 64);
        ry += __shfl_xor(ry, m, 64);
    }
    if (l < 8) {
        int c0 = l * 2;
        float2 o;
        o.x = rx * 0.125f + b2[c0];
        o.y = ry * 0.125f + b2[c0 + 1];
        *(float2*)(out + (size_t)n * 16 + c0) = o;
    }
}

// ---------------- launch ----------------

extern "C" void kernel_launch(void* const* d_in, const int* in_sizes, int n_in,
                              void* d_out, int out_size, void* d_ws, size_t ws_size,
                              hipStream_t stream) {
    (void)n_in; (void)out_size; (void)ws_size;
    const float* x      = (const float*)d_in[0];
    const int*   ei     = (const int*)d_in[1];
    const float* W1     = (const float*)d_in[2];
    const float* a_src1 = (const float*)d_in[3];
    const float* a_dst1 = (const float*)d_in[4];
    const float* b1     = (const float*)d_in[5];
    const float* W2     = (const float*)d_in[6];
    const float* a_src2 = (const float*)d_in[7];
    const float* a_dst2 = (const float*)d_in[8];
    const float* b2     = (const float*)d_in[9];

    int N = in_sizes[0] / 512;
    int E = in_sizes[1] / 2;
    const int* src = ei;
    const int* dst = ei + E;
    int NB = (N + 511) >> 9;  // 196 for N=100000; LDS arrays assume <= 256

    char* ws = (char*)d_ws;
    size_t off = 0;
    auto alloc = [&](size_t bytes) -> void* {
        void* p = ws + off;
        off = (off + bytes + 255) & ~(size_t)255;
        return p;
    };
    __half* h1  = (__half*)alloc((size_t)N * 64 * 2);
    float*  h1o = (float*)alloc((size_t)N * 64 * 4);
    __half* h2  = (__half*)alloc((size_t)N * 128 * 2);
    float* as1  = (float*)alloc((size_t)N * 8 * 4);
    float* ad1  = (float*)alloc((size_t)N * 8 * 4);
    float* as2  = (float*)alloc((size_t)N * 8 * 4);
    float* ad2  = (float*)alloc((size_t)N * 8 * 4);
    int* row_start = (int*)alloc((size_t)(N + 1) * 4);
    int* bhist     = (int*)alloc(256 * 4);
    int* bbase     = (int*)alloc(257 * 4);
    int* cursor    = (int*)alloc(256 * 4);
    unsigned int* part = (unsigned int*)alloc((size_t)E * 4);
    int* csr       = (int*)alloc((size_t)E * 4);

    // --- bucketed CSR build (shared by both layers; self-loops folded analytically) ---
    hipMemsetAsync(bhist, 0, 256 * 4, stream);
    bucket_hist_k<<<512, 256, 0, stream>>>(dst, E, bhist, NB);
    bucket_scan_k<<<1, 256, 0, stream>>>(bhist, NB, bbase, cursor, row_start, N, E);
    partition_k<<<512, 256, 0, stream>>>(src, dst, E, cursor, part, NB);
    bucket_build_k<<<NB, 512, 0, stream>>>(part, bbase, row_start, csr, N);

    // --- layer 1 ---
    dim3 g1((N + BM - 1) / BM, 1);
    sgemm_k<<<g1, 256, 0, stream>>>(x, W1, h1, N, 64, 512);
    alpha_k<8><<<(N * 8 + 255) / 256, 256, 0, stream>>>(h1, a_src1, a_dst1, as1, ad1, N * 8);
    aggregate1_k<<<N, 64, 0, stream>>>(h1, as1, ad1, row_start, csr, b1, h1o, N);

    // --- layer 2 ---
    dim3 g2((N + BM - 1) / BM, 2);
    sgemm_k<<<g2, 256, 0, stream>>>(h1o, W2, h2, N, 128, 64);
    alpha_k<16><<<(N * 8 + 255) / 256, 256, 0, stream>>>(h2, a_src2, a_dst2, as2, ad2, N * 8);
    aggregate2_k<<<N, 64, 0, stream>>>(h2, as2, ad2, row_start, csr, b2, (float*)d_out, N);
}

// Round 4
// 714.779 us; speedup vs baseline: 1.8431x; 1.0467x over previous
//
#include <hip/hip_runtime.h>
#include <hip/hip_bf16.h>
#include <hip/hip_fp16.h>
#include <cstddef>

#define NEG_SLOPE 0.2f

// ================= bucketed CSR build =================
// Bucket = 512 consecutive dst nodes. NB = ceil(N/512) (== 196 for N=100000, must be <= 256).
// part[] holds (src << 9) | (dst & 511) packed per edge, grouped by bucket.

__global__ __launch_bounds__(256) void bucket_hist_k(const int* __restrict__ dst, int E,
                                                     int* __restrict__ bhist, int NB) {
    __shared__ int lh[256];
    for (int t = threadIdx.x; t < 256; t += 256) lh[t] = 0;
    __syncthreads();
    int per = (E + gridDim.x - 1) / gridDim.x;
    int s = blockIdx.x * per;
    int e = min(s + per, E);
    for (int i = s + threadIdx.x; i < e; i += 256) atomicAdd(&lh[dst[i] >> 9], 1);
    __syncthreads();
    for (int t = threadIdx.x; t < NB; t += 256)
        if (lh[t]) atomicAdd(&bhist[t], lh[t]);
}

__global__ __launch_bounds__(256) void bucket_scan_k(const int* __restrict__ bhist, int NB,
                                                     int* __restrict__ bbase, int* __restrict__ cursor,
                                                     int* __restrict__ row_start, int N, int E) {
    __shared__ int tmp[256];
    int tid = threadIdx.x;
    int v = (tid < NB) ? bhist[tid] : 0;
    tmp[tid] = v;
    __syncthreads();
    for (int d = 1; d < 256; d <<= 1) {
        int t = tmp[tid];
        int a = (tid >= d) ? tmp[tid - d] : 0;
        __syncthreads();
        tmp[tid] = t + a;
        __syncthreads();
    }
    if (tid < NB) {
        int b = tmp[tid] - v;  // exclusive
        bbase[tid] = b;
        cursor[tid] = b;
    }
    if (tid == 0) {
        bbase[NB] = E;
        row_start[N] = E;
    }
}

__global__ __launch_bounds__(256) void partition_k(const int* __restrict__ src,
                                                   const int* __restrict__ dst, int E,
                                                   int* __restrict__ cursor,
                                                   unsigned int* __restrict__ part, int NB) {
    __shared__ int lh[256];
    __shared__ int lbase[256];
    for (int t = threadIdx.x; t < 256; t += 256) lh[t] = 0;
    __syncthreads();
    int per = (E + gridDim.x - 1) / gridDim.x;
    int s = blockIdx.x * per;
    int e = min(s + per, E);
    for (int i = s + threadIdx.x; i < e; i += 256) atomicAdd(&lh[dst[i] >> 9], 1);
    __syncthreads();
    for (int t = threadIdx.x; t < NB; t += 256) {
        int c = lh[t];
        lbase[t] = c ? atomicAdd(&cursor[t], c) : 0;
        lh[t] = 0;  // becomes local cursor
    }
    __syncthreads();
    for (int i = s + threadIdx.x; i < e; i += 256) {
        int d = dst[i];
        int b = d >> 9;
        int lo = atomicAdd(&lh[b], 1);
        part[lbase[b] + lo] = ((unsigned)src[i] << 9) | (unsigned)(d & 511);
    }
}

// One workgroup per bucket: per-node counts + scan in LDS -> row_start; then scatter
// src ids into the bucket's contiguous csr window (L2-resident, ~64 KB).
__global__ __launch_bounds__(512) void bucket_build_k(const unsigned int* __restrict__ part,
                                                      const int* __restrict__ bbase,
                                                      int* __restrict__ row_start,
                                                      int* __restrict__ csr, int N) {
    __shared__ int cnt[512];
    __shared__ int cur[512];
    int b = blockIdx.x, tid = threadIdx.x;
    int n0 = b << 9;
    int s = bbase[b], e2 = bbase[b + 1];
    cnt[tid] = 0;
    __syncthreads();
    for (int i = s + tid; i < e2; i += 512) atomicAdd(&cnt[part[i] & 511], 1);
    __syncthreads();
    int v = cnt[tid];
    for (int d = 1; d < 512; d <<= 1) {  // inclusive scan, in place
        int t = cnt[tid];
        int a = (tid >= d) ? cnt[tid - d] : 0;
        __syncthreads();
        cnt[tid] = t + a;
        __syncthreads();
    }
    int excl = cnt[tid] - v;
    if (n0 + tid < N) row_start[n0 + tid] = s + excl;
    cur[tid] = excl;
    __syncthreads();
    for (int i = s + tid; i < e2; i += 512) {
        unsigned u = part[i];
        int p = atomicAdd(&cur[u & 511], 1);
        csr[s + p] = (int)(u >> 9);
    }
}

// ---------------- SGEMM (fp32 accumulate, fp16 output, LDS-tiled, 4x4/thread) ----
// C[M,Nc] = A[M,K] @ B[K,Nc]; K % 32 == 0, Nc % 64 == 0. C stored as __half.

#define BM 64
#define BN 64
#define BKT 32

__global__ __launch_bounds__(256) void sgemm_k(const float* __restrict__ A,
                                               const float* __restrict__ B,
                                               __half* __restrict__ C,
                                               int M, int Nc, int K) {
    __shared__ __align__(16) float As[BKT][BM + 4];
    __shared__ __align__(16) float Bs[BKT][BN];
    int bm = blockIdx.x * BM;
    int bn = blockIdx.y * BN;
    int t = threadIdx.x;
    int tc = t & 15;
    int tr = t >> 4;
    float acc[4][4] = {};

    for (int k0 = 0; k0 < K; k0 += BKT) {
        {
            int row = t >> 3;
            int kk = (t & 7) << 2;
#pragma unroll
            for (int p = 0; p < 2; ++p) {
                int r = row + p * 32;
                int gr = bm + r;
                float4 v = make_float4(0.f, 0.f, 0.f, 0.f);
                if (gr < M) v = *(const float4*)(A + (size_t)gr * K + k0 + kk);
                As[kk + 0][r] = v.x; As[kk + 1][r] = v.y;
                As[kk + 2][r] = v.z; As[kk + 3][r] = v.w;
            }
        }
        {
            int bk = t >> 4;
            int cc = (t & 15) << 2;
#pragma unroll
            for (int p = 0; p < 2; ++p) {
                int k = bk + p * 16;
                *(float4*)(&Bs[k][cc]) = *(const float4*)(B + (size_t)(k0 + k) * Nc + bn + cc);
            }
        }
        __syncthreads();
#pragma unroll
        for (int kk2 = 0; kk2 < BKT; ++kk2) {
            float4 a4 = *(const float4*)(&As[kk2][tr << 2]);
            float4 b4 = *(const float4*)(&Bs[kk2][tc << 2]);
            float av[4] = {a4.x, a4.y, a4.z, a4.w};
            float bv[4] = {b4.x, b4.y, b4.z, b4.w};
#pragma unroll
            for (int i = 0; i < 4; ++i)
#pragma unroll
                for (int j = 0; j < 4; ++j)
                    acc[i][j] = fmaf(av[i], bv[j], acc[i][j]);
        }
        __syncthreads();
    }
#pragma unroll
    for (int i = 0; i < 4; ++i) {
        int gr = bm + (tr << 2) + i;
        if (gr < M) {
            ushort4 p;
            p.x = __half_as_ushort(__float2half(acc[i][0]));
            p.y = __half_as_ushort(__float2half(acc[i][1]));
            p.z = __half_as_ushort(__float2half(acc[i][2]));
            p.w = __half_as_ushort(__float2half(acc[i][3]));
            *(ushort4*)(C + (size_t)gr * Nc + bn + (tc << 2)) = p;
        }
    }
}

// ---------------- attention scores: alpha_s/alpha_d per (node, head) ----------------

template <int C>
__global__ void alpha_k(const __half* __restrict__ h, const float* __restrict__ a_s,
                        const float* __restrict__ a_d, float* __restrict__ os,
                        float* __restrict__ od, int NH) {
    int i = blockIdx.x * 256 + threadIdx.x;  // i = n*8 + head
    if (i >= NH) return;
    int hh = i & 7;
    const __half* hp = h + (size_t)i * C;
    float s = 0.f, d = 0.f;
#pragma unroll
    for (int c = 0; c < C; ++c) {
        float v = __half2float(hp[c]);
        s = fmaf(v, a_s[hh * C + c], s);
        d = fmaf(v, a_d[hh * C + c], d);
    }
    os[i] = s;
    od[i] = d;
}

// ---------------- layer 1 aggregation: one 64-lane wave per dst node ----------------
// lane l -> (head = l>>3, ch = l&7); h1 layout [n][h*8+c] = [n][l], fp16.
// 8-edge batches: phase A lane l computes exp for (edge l&7, head l>>3) -- one
// v_exp_f32 covers 8 edges x 8 heads; phase B broadcasts via readlane/bpermute.

__global__ __launch_bounds__(64) void aggregate1_k(
    const __half* __restrict__ h1, const float* __restrict__ as,
    const float* __restrict__ ad, const int* __restrict__ row_start,
    const int* __restrict__ csr, const float* __restrict__ b1,
    float* __restrict__ h1o, int N) {
    int n = blockIdx.x;
    int l = threadIdx.x;
    int h = l >> 3;
    int j = l & 7;
    int lbase = l & 56;
    float adv = ad[n * 8 + h];
    float e0 = as[n * 8 + h] + adv;
    e0 = fmaxf(e0, NEG_SLOPE * e0);
    float ex0 = __expf(e0);
    float denom = ex0;
    float acc = ex0 * __half2float(h1[(size_t)n * 64 + l]);
    int e = row_start[n], end = row_start[n + 1];
    int batched = e + ((end - e) & ~7);
    for (; e < batched; e += 8) {
        int sj = csr[e + j];                     // edge (l&7)'s src
        float aj = as[sj * 8 + h];               // (edge j, head h)
        float t = aj + adv;
        t = fmaxf(t, NEG_SLOPE * t);
        float xj = __expf(t);                    // one exp per (edge,head) pair
#pragma unroll
        for (int q = 0; q < 8; ++q) {
            int sq = __shfl(sj, q, 64);          // wave-uniform src of edge q
            float xq = __shfl(xj, lbase + q, 64);// exp(edge q, my head)
            float v = __half2float(h1[(size_t)sq * 64 + l]);
            denom += xq;
            acc = fmaf(xq, v, acc);
        }
    }
    for (; e < end; ++e) {
        int s0 = csr[e];
        float t = as[s0 * 8 + h] + adv;
        t = fmaxf(t, NEG_SLOPE * t);
        float x0 = __expf(t);
        denom += x0;
        acc = fmaf(x0, __half2float(h1[(size_t)s0 * 64 + l]), acc);
    }
    float v = acc / denom + b1[l];
    h1o[(size_t)n * 64 + l] = v > 0.f ? v : expm1f(v);  // ELU
}

// ---------------- layer 2 aggregation: one wave per dst node, half2 lanes ---------
// lane l -> (head = l>>3, cpair = l&7 -> channels 2*cpair, 2*cpair+1); h2 fp16.
// Same 8-edge batched-exp structure as aggregate1_k.

__global__ __launch_bounds__(64) void aggregate2_k(
    const __half* __restrict__ h2, const float* __restrict__ as,
    const float* __restrict__ ad, const int* __restrict__ row_start,
    const int* __restrict__ csr, const float* __restrict__ b2,
    float* __restrict__ out, int N) {
    int n = blockIdx.x;
    int l = threadIdx.x;
    int h = l >> 3;
    int j = l & 7;
    int lbase = l & 56;
    const __half2* H = (const __half2*)h2;  // [n][64] half2
    float adv = ad[n * 8 + h];
    float e0 = as[n * 8 + h] + adv;
    e0 = fmaxf(e0, NEG_SLOPE * e0);
    float ex0 = __expf(e0);
    float denom = ex0;
    float2 self = __half22float2(H[(size_t)n * 64 + l]);
    float accx = ex0 * self.x, accy = ex0 * self.y;
    int e = row_start[n], end = row_start[n + 1];
    int batched = e + ((end - e) & ~7);
    for (; e < batched; e += 8) {
        int sj = csr[e + j];
        float aj = as[sj * 8 + h];
        float t = aj + adv;
        t = fmaxf(t, NEG_SLOPE * t);
        float xj = __expf(t);
#pragma unroll
        for (int q = 0; q < 8; ++q) {
            int sq = __shfl(sj, q, 64);
            float xq = __shfl(xj, lbase + q, 64);
            float2 v = __half22float2(H[(size_t)sq * 64 + l]);
            denom += xq;
            accx = fmaf(xq, v.x, accx);
            accy = fmaf(xq, v.y, accy);
        }
    }
    for (; e < end; ++e) {
        int s0 = csr[e];
        float t = as[s0 * 8 + h] + adv;
        t = fmaxf(t, NEG_SLOPE * t);
        float x0 = __expf(t);
        float2 v = __half22float2(H[(size_t)s0 * 64 + l]);
        denom += x0;
        accx = fmaf(x0, v.x, accx);
        accy = fmaf(x0, v.y, accy);
    }
    float rx = accx / denom, ry = accy / denom;
#pragma unroll
    for (int m = 8; m <= 32; m <<= 1) {
        rx += __shfl_xor(rx, m, 64);
        ry += __shfl_xor(ry, m, 64);
    }
    if (l < 8) {
        int c0 = l * 2;
        float2 o;
        o.x = rx * 0.125f + b2[c0];
        o.y = ry * 0.125f + b2[c0 + 1];
        *(float2*)(out + (size_t)n * 16 + c0) = o;
    }
}

// ---------------- launch ----------------

extern "C" void kernel_launch(void* const* d_in, const int* in_sizes, int n_in,
                              void* d_out, int out_size, void* d_ws, size_t ws_size,
                              hipStream_t stream) {
    (void)n_in; (void)out_size; (void)ws_size;
    const float* x      = (const float*)d_in[0];
    const int*   ei     = (const int*)d_in[1];
    const float* W1     = (const float*)d_in[2];
    const float* a_src1 = (const float*)d_in[3];
    const float* a_dst1 = (const float*)d_in[4];
    const float* b1     = (const float*)d_in[5];
    const float* W2     = (const float*)d_in[6];
    const float* a_src2 = (const float*)d_in[7];
    const float* a_dst2 = (const float*)d_in[8];
    const float* b2     = (const float*)d_in[9];

    int N = in_sizes[0] / 512;
    int E = in_sizes[1] / 2;
    const int* src = ei;
    const int* dst = ei + E;
    int NB = (N + 511) >> 9;  // 196 for N=100000; LDS arrays assume <= 256

    char* ws = (char*)d_ws;
    size_t off = 0;
    auto alloc = [&](size_t bytes) -> void* {
        void* p = ws + off;
        off = (off + bytes + 255) & ~(size_t)255;
        return p;
    };
    __half* h1  = (__half*)alloc((size_t)N * 64 * 2);
    float*  h1o = (float*)alloc((size_t)N * 64 * 4);
    __half* h2  = (__half*)alloc((size_t)N * 128 * 2);
    float* as1  = (float*)alloc((size_t)N * 8 * 4);
    float* ad1  = (float*)alloc((size_t)N * 8 * 4);
    float* as2  = (float*)alloc((size_t)N * 8 * 4);
    float* ad2  = (float*)alloc((size_t)N * 8 * 4);
    int* row_start = (int*)alloc((size_t)(N + 1) * 4);
    int* bhist     = (int*)alloc(256 * 4);
    int* bbase     = (int*)alloc(257 * 4);
    int* cursor    = (int*)alloc(256 * 4);
    unsigned int* part = (unsigned int*)alloc((size_t)E * 4);
    int* csr       = (int*)alloc((size_t)E * 4);

    // --- bucketed CSR build (shared by both layers; self-loops folded analytically) ---
    hipMemsetAsync(bhist, 0, 256 * 4, stream);
    bucket_hist_k<<<512, 256, 0, stream>>>(dst, E, bhist, NB);
    bucket_scan_k<<<1, 256, 0, stream>>>(bhist, NB, bbase, cursor, row_start, N, E);
    partition_k<<<512, 256, 0, stream>>>(src, dst, E, cursor, part, NB);
    bucket_build_k<<<NB, 512, 0, stream>>>(part, bbase, row_start, csr, N);

    // --- layer 1 ---
    dim3 g1((N + BM - 1) / BM, 1);
    sgemm_k<<<g1, 256, 0, stream>>>(x, W1, h1, N, 64, 512);
    alpha_k<8><<<(N * 8 + 255) / 256, 256, 0, stream>>>(h1, a_src1, a_dst1, as1, ad1, N * 8);
    aggregate1_k<<<N, 64, 0, stream>>>(h1, as1, ad1, row_start, csr, b1, h1o, N);

    // --- layer 2 ---
    dim3 g2((N + BM - 1) / BM, 2);
    sgemm_k<<<g2, 256, 0, stream>>>(h1o, W2, h2, N, 128, 64);
    alpha_k<16><<<(N * 8 + 255) / 256, 256, 0, stream>>>(h2, a_src2, a_dst2, as2, ad2, N * 8);
    aggregate2_k<<<N, 64, 0, stream>>>(h2, as2, ad2, row_start, csr, b2, (float*)d_out, N);
}

// Round 5
// 697.364 us; speedup vs baseline: 1.8891x; 1.0250x over previous
//
#include <hip/hip_runtime.h>
#include <hip/hip_bf16.h>
#include <hip/hip_fp16.h>
#include <cstddef>

#define NEG_SLOPE 0.2f

typedef _Float16 half8 __attribute__((ext_vector_type(8)));
typedef float floatx4 __attribute__((ext_vector_type(4)));

// ================= bucketed CSR build =================
// Bucket = 512 consecutive dst nodes. NB = ceil(N/512) (== 196 for N=100000, must be <= 256).
// part[] holds (src << 9) | (dst & 511) packed per edge, grouped by bucket.

__global__ __launch_bounds__(256) void bucket_hist_k(const int* __restrict__ dst, int E,
                                                     int* __restrict__ bhist, int NB) {
    __shared__ int lh[256];
    for (int t = threadIdx.x; t < 256; t += 256) lh[t] = 0;
    __syncthreads();
    int per = (E + gridDim.x - 1) / gridDim.x;
    int s = blockIdx.x * per;
    int e = min(s + per, E);
    for (int i = s + threadIdx.x; i < e; i += 256) atomicAdd(&lh[dst[i] >> 9], 1);
    __syncthreads();
    for (int t = threadIdx.x; t < NB; t += 256)
        if (lh[t]) atomicAdd(&bhist[t], lh[t]);
}

__global__ __launch_bounds__(256) void bucket_scan_k(const int* __restrict__ bhist, int NB,
                                                     int* __restrict__ bbase, int* __restrict__ cursor,
                                                     int* __restrict__ row_start, int N, int E) {
    __shared__ int tmp[256];
    int tid = threadIdx.x;
    int v = (tid < NB) ? bhist[tid] : 0;
    tmp[tid] = v;
    __syncthreads();
    for (int d = 1; d < 256; d <<= 1) {
        int t = tmp[tid];
        int a = (tid >= d) ? tmp[tid - d] : 0;
        __syncthreads();
        tmp[tid] = t + a;
        __syncthreads();
    }
    if (tid < NB) {
        int b = tmp[tid] - v;  // exclusive
        bbase[tid] = b;
        cursor[tid] = b;
    }
    if (tid == 0) {
        bbase[NB] = E;
        row_start[N] = E;
    }
}

__global__ __launch_bounds__(256) void partition_k(const int* __restrict__ src,
                                                   const int* __restrict__ dst, int E,
                                                   int* __restrict__ cursor,
                                                   unsigned int* __restrict__ part, int NB) {
    __shared__ int lh[256];
    __shared__ int lbase[256];
    for (int t = threadIdx.x; t < 256; t += 256) lh[t] = 0;
    __syncthreads();
    int per = (E + gridDim.x - 1) / gridDim.x;
    int s = blockIdx.x * per;
    int e = min(s + per, E);
    for (int i = s + threadIdx.x; i < e; i += 256) atomicAdd(&lh[dst[i] >> 9], 1);
    __syncthreads();
    for (int t = threadIdx.x; t < NB; t += 256) {
        int c = lh[t];
        lbase[t] = c ? atomicAdd(&cursor[t], c) : 0;
        lh[t] = 0;  // becomes local cursor
    }
    __syncthreads();
    for (int i = s + threadIdx.x; i < e; i += 256) {
        int d = dst[i];
        int b = d >> 9;
        int lo = atomicAdd(&lh[b], 1);
        part[lbase[b] + lo] = ((unsigned)src[i] << 9) | (unsigned)(d & 511);
    }
}

// One workgroup per bucket: per-node counts + scan in LDS -> row_start; then scatter
// src ids into the bucket's contiguous csr window (L2-resident, ~64 KB).
__global__ __launch_bounds__(512) void bucket_build_k(const unsigned int* __restrict__ part,
                                                      const int* __restrict__ bbase,
                                                      int* __restrict__ row_start,
                                                      int* __restrict__ csr, int N) {
    __shared__ int cnt[512];
    __shared__ int cur[512];
    int b = blockIdx.x, tid = threadIdx.x;
    int n0 = b << 9;
    int s = bbase[b], e2 = bbase[b + 1];
    cnt[tid] = 0;
    __syncthreads();
    for (int i = s + tid; i < e2; i += 512) atomicAdd(&cnt[part[i] & 511], 1);
    __syncthreads();
    int v = cnt[tid];
    for (int d = 1; d < 512; d <<= 1) {  // inclusive scan, in place
        int t = cnt[tid];
        int a = (tid >= d) ? cnt[tid - d] : 0;
        __syncthreads();
        cnt[tid] = t + a;
        __syncthreads();
    }
    int excl = cnt[tid] - v;
    if (n0 + tid < N) row_start[n0 + tid] = s + excl;
    cur[tid] = excl;
    __syncthreads();
    for (int i = s + tid; i < e2; i += 512) {
        unsigned u = part[i];
        int p = atomicAdd(&cur[u & 511], 1);
        csr[s + p] = (int)(u >> 9);
    }
}

// ---------------- W transpose+convert: W [K][Nc] fp32 -> WT [Nc][K] f16 ----------------

__global__ void convw_k(const float* __restrict__ W, _Float16* __restrict__ WT,
                        int K, int Nc) {
    int i = blockIdx.x * 256 + threadIdx.x;
    if (i < K * Nc) {
        int k = i / Nc, n = i % Nc;
        WT[(size_t)n * K + k] = (_Float16)W[i];
    }
}

// ---------------- MFMA f16 GEMM: C[M,Nc] = A[M,K] @ BT[Nc,K]^T, fp32 accumulate ----
// Block = 4 waves x 16 M-rows = 64 rows; N covered fully (NT = Nc/16 tiles per wave).
// A loaded straight from global per fragment (fp32 variant converts inline);
// BT is f16 [Nc][K] (L2-resident, <=64 KB). No LDS.
// Fragment layouts (m89/m120-verified): A[m=lane&15][k=quad*8+j];
// B[k=quad*8+j][n=lane&15]; C/D col=lane&15, row=quad*4+reg.

template <int NT, int K, bool AF32>
__global__ __launch_bounds__(256) void mfma_gemm_k(const void* __restrict__ Av,
                                                   const _Float16* __restrict__ BT,
                                                   __half* __restrict__ C, int M) {
    constexpr int Nc = NT * 16;
    int wave = threadIdx.x >> 6, lane = threadIdx.x & 63;
    int m16 = lane & 15, quad = lane >> 4;
    int arow = blockIdx.x * 64 + wave * 16 + m16;
    int arc = arow < M ? arow : M - 1;  // clamp: OOB rows compute garbage, never stored
    floatx4 acc[NT] = {};
    for (int k0 = 0; k0 < K; k0 += 32) {
        half8 af;
        if constexpr (AF32) {
            const float* ap = (const float*)Av + (size_t)arc * K + k0 + quad * 8;
            float4 v0 = *(const float4*)ap;
            float4 v1 = *(const float4*)(ap + 4);
            af[0] = (_Float16)v0.x; af[1] = (_Float16)v0.y;
            af[2] = (_Float16)v0.z; af[3] = (_Float16)v0.w;
            af[4] = (_Float16)v1.x; af[5] = (_Float16)v1.y;
            af[6] = (_Float16)v1.z; af[7] = (_Float16)v1.w;
        } else {
            af = *(const half8*)((const _Float16*)Av + (size_t)arc * K + k0 + quad * 8);
        }
#pragma unroll
        for (int t = 0; t < NT; ++t) {
            half8 bf = *(const half8*)(BT + (size_t)(t * 16 + m16) * K + k0 + quad * 8);
            acc[t] = __builtin_amdgcn_mfma_f32_16x16x32_f16(af, bf, acc[t], 0, 0, 0);
        }
    }
    int gm0 = blockIdx.x * 64 + wave * 16 + quad * 4;
#pragma unroll
    for (int t = 0; t < NT; ++t)
#pragma unroll
        for (int r = 0; r < 4; ++r) {
            int gm = gm0 + r;
            if (gm < M) C[(size_t)gm * Nc + t * 16 + m16] = __float2half(acc[t][r]);
        }
}

// ---------------- attention scores: alpha_s/alpha_d per (node, head) ----------------

template <int C>
__global__ void alpha_k(const __half* __restrict__ h, const float* __restrict__ a_s,
                        const float* __restrict__ a_d, float* __restrict__ os,
                        float* __restrict__ od, int NH) {
    int i = blockIdx.x * 256 + threadIdx.x;  // i = n*8 + head
    if (i >= NH) return;
    int hh = i & 7;
    const __half* hp = h + (size_t)i * C;
    float s = 0.f, d = 0.f;
#pragma unroll
    for (int c = 0; c < C; ++c) {
        float v = __half2float(hp[c]);
        s = fmaf(v, a_s[hh * C + c], s);
        d = fmaf(v, a_d[hh * C + c], d);
    }
    os[i] = s;
    od[i] = d;
}

// ---------------- layer 1 aggregation: one 64-lane wave per dst node ----------------
// lane l -> (head = l>>3, ch = l&7); h1 layout [n][h*8+c] = [n][l], fp16.
// 8-edge batches: phase A lane l computes exp for (edge l&7, head l>>3) -- one
// v_exp_f32 covers 8 edges x 8 heads; phase B broadcasts via readlane/bpermute.

__global__ __launch_bounds__(64) void aggregate1_k(
    const __half* __restrict__ h1, const float* __restrict__ as,
    const float* __restrict__ ad, const int* __restrict__ row_start,
    const int* __restrict__ csr, const float* __restrict__ b1,
    __half* __restrict__ h1o, int N) {
    int n = blockIdx.x;
    int l = threadIdx.x;
    int h = l >> 3;
    int j = l & 7;
    int lbase = l & 56;
    float adv = ad[n * 8 + h];
    float e0 = as[n * 8 + h] + adv;
    e0 = fmaxf(e0, NEG_SLOPE * e0);
    float ex0 = __expf(e0);
    float denom = ex0;
    float acc = ex0 * __half2float(h1[(size_t)n * 64 + l]);
    int e = row_start[n], end = row_start[n + 1];
    int batched = e + ((end - e) & ~7);
    for (; e < batched; e += 8) {
        int sj = csr[e + j];                     // edge (l&7)'s src
        float aj = as[sj * 8 + h];               // (edge j, head h)
        float t = aj + adv;
        t = fmaxf(t, NEG_SLOPE * t);
        float xj = __expf(t);                    // one exp per (edge,head) pair
#pragma unroll
        for (int q = 0; q < 8; ++q) {
            int sq = __shfl(sj, q, 64);          // wave-uniform src of edge q
            float xq = __shfl(xj, lbase + q, 64);// exp(edge q, my head)
            float v = __half2float(h1[(size_t)sq * 64 + l]);
            denom += xq;
            acc = fmaf(xq, v, acc);
        }
    }
    for (; e < end; ++e) {
        int s0 = csr[e];
        float t = as[s0 * 8 + h] + adv;
        t = fmaxf(t, NEG_SLOPE * t);
        float x0 = __expf(t);
        denom += x0;
        acc = fmaf(x0, __half2float(h1[(size_t)s0 * 64 + l]), acc);
    }
    float v = acc / denom + b1[l];
    h1o[(size_t)n * 64 + l] = __float2half(v > 0.f ? v : expm1f(v));  // ELU
}

// ---------------- layer 2 aggregation: one wave per dst node, half2 lanes ---------
// lane l -> (head = l>>3, cpair = l&7 -> channels 2*cpair, 2*cpair+1); h2 fp16.
// Same 8-edge batched-exp structure as aggregate1_k.

__global__ __launch_bounds__(64) void aggregate2_k(
    const __half* __restrict__ h2, const float* __restrict__ as,
    const float* __restrict__ ad, const int* __restrict__ row_start,
    const int* __restrict__ csr, const float* __restrict__ b2,
    float* __restrict__ out, int N) {
    int n = blockIdx.x;
    int l = threadIdx.x;
    int h = l >> 3;
    int j = l & 7;
    int lbase = l & 56;
    const __half2* H = (const __half2*)h2;  // [n][64] half2
    float adv = ad[n * 8 + h];
    float e0 = as[n * 8 + h] + adv;
    e0 = fmaxf(e0, NEG_SLOPE * e0);
    float ex0 = __expf(e0);
    float denom = ex0;
    float2 self = __half22float2(H[(size_t)n * 64 + l]);
    float accx = ex0 * self.x, accy = ex0 * self.y;
    int e = row_start[n], end = row_start[n + 1];
    int batched = e + ((end - e) & ~7);
    for (; e < batched; e += 8) {
        int sj = csr[e + j];
        float aj = as[sj * 8 + h];
        float t = aj + adv;
        t = fmaxf(t, NEG_SLOPE * t);
        float xj = __expf(t);
#pragma unroll
        for (int q = 0; q < 8; ++q) {
            int sq = __shfl(sj, q, 64);
            float xq = __shfl(xj, lbase + q, 64);
            float2 v = __half22float2(H[(size_t)sq * 64 + l]);
            denom += xq;
            accx = fmaf(xq, v.x, accx);
            accy = fmaf(xq, v.y, accy);
        }
    }
    for (; e < end; ++e) {
        int s0 = csr[e];
        float t = as[s0 * 8 + h] + adv;
        t = fmaxf(t, NEG_SLOPE * t);
        float x0 = __expf(t);
        float2 v = __half22float2(H[(size_t)s0 * 64 + l]);
        denom += x0;
        accx = fmaf(x0, v.x, accx);
        accy = fmaf(x0, v.y, accy);
    }
    float rx = accx / denom, ry = accy / denom;
#pragma unroll
    for (int m = 8; m <= 32; m <<= 1) {
        rx += __shfl_xor(rx, m, 64);
        ry += __shfl_xor(ry, m, 64);
    }
    if (l < 8) {
        int c0 = l * 2;
        float2 o;
        o.x = rx * 0.125f + b2[c0];
        o.y = ry * 0.125f + b2[c0 + 1];
        *(float2*)(out + (size_t)n * 16 + c0) = o;
    }
}

// ---------------- launch ----------------

extern "C" void kernel_launch(void* const* d_in, const int* in_sizes, int n_in,
                              void* d_out, int out_size, void* d_ws, size_t ws_size,
                              hipStream_t stream) {
    (void)n_in; (void)out_size; (void)ws_size;
    const float* x      = (const float*)d_in[0];
    const int*   ei     = (const int*)d_in[1];
    const float* W1     = (const float*)d_in[2];
    const float* a_src1 = (const float*)d_in[3];
    const float* a_dst1 = (const float*)d_in[4];
    const float* b1     = (const float*)d_in[5];
    const float* W2     = (const float*)d_in[6];
    const float* a_src2 = (const float*)d_in[7];
    const float* a_dst2 = (const float*)d_in[8];
    const float* b2     = (const float*)d_in[9];

    int N = in_sizes[0] / 512;
    int E = in_sizes[1] / 2;
    const int* src = ei;
    const int* dst = ei + E;
    int NB = (N + 511) >> 9;  // 196 for N=100000; LDS arrays assume <= 256

    char* ws = (char*)d_ws;
    size_t off = 0;
    auto alloc = [&](size_t bytes) -> void* {
        void* p = ws + off;
        off = (off + bytes + 255) & ~(size_t)255;
        return p;
    };
    __half* h1  = (__half*)alloc((size_t)N * 64 * 2);
    __half* h1o = (__half*)alloc((size_t)N * 64 * 2);
    __half* h2  = (__half*)alloc((size_t)N * 128 * 2);
    float* as1  = (float*)alloc((size_t)N * 8 * 4);
    float* ad1  = (float*)alloc((size_t)N * 8 * 4);
    float* as2  = (float*)alloc((size_t)N * 8 * 4);
    float* ad2  = (float*)alloc((size_t)N * 8 * 4);
    _Float16* W1T = (_Float16*)alloc((size_t)512 * 64 * 2);
    _Float16* W2T = (_Float16*)alloc((size_t)64 * 128 * 2);
    int* row_start = (int*)alloc((size_t)(N + 1) * 4);
    int* bhist     = (int*)alloc(256 * 4);
    int* bbase     = (int*)alloc(257 * 4);
    int* cursor    = (int*)alloc(256 * 4);
    unsigned int* part = (unsigned int*)alloc((size_t)E * 4);
    int* csr       = (int*)alloc((size_t)E * 4);

    // --- weight transpose+convert (tiny, L2-resident thereafter) ---
    convw_k<<<(512 * 64 + 255) / 256, 256, 0, stream>>>(W1, W1T, 512, 64);
    convw_k<<<(64 * 128 + 255) / 256, 256, 0, stream>>>(W2, W2T, 64, 128);

    // --- bucketed CSR build (shared by both layers; self-loops folded analytically) ---
    hipMemsetAsync(bhist, 0, 256 * 4, stream);
    bucket_hist_k<<<512, 256, 0, stream>>>(dst, E, bhist, NB);
    bucket_scan_k<<<1, 256, 0, stream>>>(bhist, NB, bbase, cursor, row_start, N, E);
    partition_k<<<512, 256, 0, stream>>>(src, dst, E, cursor, part, NB);
    bucket_build_k<<<NB, 512, 0, stream>>>(part, bbase, row_start, csr, N);

    int gblocks = (N + 63) / 64;

    // --- layer 1 ---
    mfma_gemm_k<4, 512, true><<<gblocks, 256, 0, stream>>>(x, W1T, h1, N);
    alpha_k<8><<<(N * 8 + 255) / 256, 256, 0, stream>>>(h1, a_src1, a_dst1, as1, ad1, N * 8);
    aggregate1_k<<<N, 64, 0, stream>>>(h1, as1, ad1, row_start, csr, b1, h1o, N);

    // --- layer 2 ---
    mfma_gemm_k<8, 64, false><<<gblocks, 256, 0, stream>>>(h1o, W2T, h2, N);
    alpha_k<16><<<(N * 8 + 255) / 256, 256, 0, stream>>>(h2, a_src2, a_dst2, as2, ad2, N * 8);
    aggregate2_k<<<N, 64, 0, stream>>>(h2, as2, ad2, row_start, csr, b2, (float*)d_out, N);
}

// Round 6
// 695.646 us; speedup vs baseline: 1.8938x; 1.0025x over previous
//
#include <hip/hip_runtime.h>
#include <hip/hip_bf16.h>
#include <hip/hip_fp16.h>
#include <cstddef>

#define NEG_SLOPE 0.2f
#define CHUNK_SHIFT 14  // src-chunk = src>>14: 16K nodes -> 4 MB of h2 / 2 MB of h1 per chunk

typedef _Float16 half8 __attribute__((ext_vector_type(8)));
typedef float floatx4 __attribute__((ext_vector_type(4)));

// ================= bucketed CSR build =================
// Bucket = 512 consecutive dst nodes. NB = ceil(N/512) (== 196 for N=100000, must be <= 256).
// part[] holds (src << 9) | (dst & 511) packed per edge, grouped by bucket.
// bucket_build additionally orders each node's list by src-chunk (src>>CHUNK_SHIFT) so
// that co-resident aggregate waves sweep h[] chunk-by-chunk -> XCD-L2-resident gathers.

__global__ __launch_bounds__(256) void bucket_hist_k(const int* __restrict__ dst, int E,
                                                     int* __restrict__ bhist, int NB) {
    __shared__ int lh[256];
    for (int t = threadIdx.x; t < 256; t += 256) lh[t] = 0;
    __syncthreads();
    int per = (E + gridDim.x - 1) / gridDim.x;
    int s = blockIdx.x * per;
    int e = min(s + per, E);
    for (int i = s + threadIdx.x; i < e; i += 256) atomicAdd(&lh[dst[i] >> 9], 1);
    __syncthreads();
    for (int t = threadIdx.x; t < NB; t += 256)
        if (lh[t]) atomicAdd(&bhist[t], lh[t]);
}

__global__ __launch_bounds__(256) void bucket_scan_k(const int* __restrict__ bhist, int NB,
                                                     int* __restrict__ bbase, int* __restrict__ cursor,
                                                     int* __restrict__ row_start, int N, int E) {
    __shared__ int tmp[256];
    int tid = threadIdx.x;
    int v = (tid < NB) ? bhist[tid] : 0;
    tmp[tid] = v;
    __syncthreads();
    for (int d = 1; d < 256; d <<= 1) {
        int t = tmp[tid];
        int a = (tid >= d) ? tmp[tid - d] : 0;
        __syncthreads();
        tmp[tid] = t + a;
        __syncthreads();
    }
    if (tid < NB) {
        int b = tmp[tid] - v;  // exclusive
        bbase[tid] = b;
        cursor[tid] = b;
    }
    if (tid == 0) {
        bbase[NB] = E;
        row_start[N] = E;
    }
}

__global__ __launch_bounds__(256) void partition_k(const int* __restrict__ src,
                                                   const int* __restrict__ dst, int E,
                                                   int* __restrict__ cursor,
                                                   unsigned int* __restrict__ part, int NB) {
    __shared__ int lh[256];
    __shared__ int lbase[256];
    for (int t = threadIdx.x; t < 256; t += 256) lh[t] = 0;
    __syncthreads();
    int per = (E + gridDim.x - 1) / gridDim.x;
    int s = blockIdx.x * per;
    int e = min(s + per, E);
    for (int i = s + threadIdx.x; i < e; i += 256) atomicAdd(&lh[dst[i] >> 9], 1);
    __syncthreads();
    for (int t = threadIdx.x; t < NB; t += 256) {
        int c = lh[t];
        lbase[t] = c ? atomicAdd(&cursor[t], c) : 0;
        lh[t] = 0;  // becomes local cursor
    }
    __syncthreads();
    for (int i = s + threadIdx.x; i < e; i += 256) {
        int d = dst[i];
        int b = d >> 9;
        int lo = atomicAdd(&lh[b], 1);
        part[lbase[b] + lo] = ((unsigned)src[i] << 9) | (unsigned)(d & 511);
    }
}

// One workgroup per bucket: per-(node,chunk) counts + two-level scan in LDS ->
// row_start AND src-chunk-sorted adjacency; scatter into the bucket's contiguous
// csr window (L2-resident, ~64 KB).
__global__ __launch_bounds__(512) void bucket_build_k(const unsigned int* __restrict__ part,
                                                      const int* __restrict__ bbase,
                                                      int* __restrict__ row_start,
                                                      int* __restrict__ csr, int N) {
    __shared__ int cnt2[512 * 8];   // per-(node, src-chunk) counters -> cursors
    __shared__ int nsum[512];
    int b = blockIdx.x, tid = threadIdx.x;
    int n0 = b << 9;
    int s = bbase[b], e2 = bbase[b + 1];
    for (int i = tid; i < 4096; i += 512) cnt2[i] = 0;
    __syncthreads();
    for (int i = s + tid; i < e2; i += 512) {
        unsigned u = part[i];
        atomicAdd(&cnt2[(u & 511) * 8 + ((u >> 9) >> CHUNK_SHIFT)], 1);
    }
    __syncthreads();
    int tot = 0;
#pragma unroll
    for (int c = 0; c < 8; ++c) tot += cnt2[tid * 8 + c];
    nsum[tid] = tot;
    __syncthreads();
    for (int d = 1; d < 512; d <<= 1) {  // inclusive scan over node totals
        int t = nsum[tid];
        int a = (tid >= d) ? nsum[tid - d] : 0;
        __syncthreads();
        nsum[tid] = t + a;
        __syncthreads();
    }
    int excl = nsum[tid] - tot;          // node-level exclusive offset in segment
    if (n0 + tid < N) row_start[n0 + tid] = s + excl;
    int run = excl;                      // per-node chunk-level exclusive scan -> cursors
#pragma unroll
    for (int c = 0; c < 8; ++c) {
        int v = cnt2[tid * 8 + c];
        cnt2[tid * 8 + c] = run;
        run += v;
    }
    __syncthreads();
    for (int i = s + tid; i < e2; i += 512) {
        unsigned u = part[i];
        int srcv = (int)(u >> 9);
        int p = atomicAdd(&cnt2[(u & 511) * 8 + (srcv >> CHUNK_SHIFT)], 1);
        csr[s + p] = srcv;
    }
}

// ---------------- W transpose+convert: W [K][Nc] fp32 -> WT [Nc][K] f16 ----------------

__global__ void convw_k(const float* __restrict__ W, _Float16* __restrict__ WT,
                        int K, int Nc) {
    int i = blockIdx.x * 256 + threadIdx.x;
    if (i < K * Nc) {
        int k = i / Nc, n = i % Nc;
        WT[(size_t)n * K + k] = (_Float16)W[i];
    }
}

// ---------------- MFMA f16 GEMM: C[M,Nc] = A[M,K] @ BT[Nc,K]^T, fp32 accumulate ----
// Block = 4 waves x 16 M-rows = 64 rows; N covered fully (NT = Nc/16 tiles per wave).
// A loaded straight from global per fragment (fp32 variant converts inline);
// BT is f16 [Nc][K] (L2-resident, <=64 KB). No LDS.
// Fragment layouts (m89/m120-verified): A[m=lane&15][k=quad*8+j];
// B[k=quad*8+j][n=lane&15]; C/D col=lane&15, row=quad*4+reg.

template <int NT, int K, bool AF32>
__global__ __launch_bounds__(256) void mfma_gemm_k(const void* __restrict__ Av,
                                                   const _Float16* __restrict__ BT,
                                                   __half* __restrict__ C, int M) {
    constexpr int Nc = NT * 16;
    int wave = threadIdx.x >> 6, lane = threadIdx.x & 63;
    int m16 = lane & 15, quad = lane >> 4;
    int arow = blockIdx.x * 64 + wave * 16 + m16;
    int arc = arow < M ? arow : M - 1;  // clamp: OOB rows compute garbage, never stored
    floatx4 acc[NT] = {};
    for (int k0 = 0; k0 < K; k0 += 32) {
        half8 af;
        if constexpr (AF32) {
            const float* ap = (const float*)Av + (size_t)arc * K + k0 + quad * 8;
            float4 v0 = *(const float4*)ap;
            float4 v1 = *(const float4*)(ap + 4);
            af[0] = (_Float16)v0.x; af[1] = (_Float16)v0.y;
            af[2] = (_Float16)v0.z; af[3] = (_Float16)v0.w;
            af[4] = (_Float16)v1.x; af[5] = (_Float16)v1.y;
            af[6] = (_Float16)v1.z; af[7] = (_Float16)v1.w;
        } else {
            af = *(const half8*)((const _Float16*)Av + (size_t)arc * K + k0 + quad * 8);
        }
#pragma unroll
        for (int t = 0; t < NT; ++t) {
            half8 bf = *(const half8*)(BT + (size_t)(t * 16 + m16) * K + k0 + quad * 8);
            acc[t] = __builtin_amdgcn_mfma_f32_16x16x32_f16(af, bf, acc[t], 0, 0, 0);
        }
    }
    int gm0 = blockIdx.x * 64 + wave * 16 + quad * 4;
#pragma unroll
    for (int t = 0; t < NT; ++t)
#pragma unroll
        for (int r = 0; r < 4; ++r) {
            int gm = gm0 + r;
            if (gm < M) C[(size_t)gm * Nc + t * 16 + m16] = __float2half(acc[t][r]);
        }
}

// ---------------- attention scores: alpha_s/alpha_d per (node, head) ----------------

template <int C>
__global__ void alpha_k(const __half* __restrict__ h, const float* __restrict__ a_s,
                        const float* __restrict__ a_d, float* __restrict__ os,
                        float* __restrict__ od, int NH) {
    int i = blockIdx.x * 256 + threadIdx.x;  // i = n*8 + head
    if (i >= NH) return;
    int hh = i & 7;
    const __half* hp = h + (size_t)i * C;
    float s = 0.f, d = 0.f;
#pragma unroll
    for (int c = 0; c < C; ++c) {
        float v = __half2float(hp[c]);
        s = fmaf(v, a_s[hh * C + c], s);
        d = fmaf(v, a_d[hh * C + c], d);
    }
    os[i] = s;
    od[i] = d;
}

// ---------------- layer 1 aggregation: one 64-lane wave per dst node ----------------
// lane l -> (head = l>>3, ch = l&7); h1 layout [n][h*8+c] = [n][l], fp16.
// 8-edge batches: phase A lane l computes exp for (edge l&7, head l>>3) -- one
// v_exp_f32 covers 8 edges x 8 heads; phase B broadcasts via readlane/bpermute.

__global__ __launch_bounds__(64) void aggregate1_k(
    const __half* __restrict__ h1, const float* __restrict__ as,
    const float* __restrict__ ad, const int* __restrict__ row_start,
    const int* __restrict__ csr, const float* __restrict__ b1,
    __half* __restrict__ h1o, int N) {
    int n = blockIdx.x;
    int l = threadIdx.x;
    int h = l >> 3;
    int j = l & 7;
    int lbase = l & 56;
    float adv = ad[n * 8 + h];
    float e0 = as[n * 8 + h] + adv;
    e0 = fmaxf(e0, NEG_SLOPE * e0);
    float ex0 = __expf(e0);
    float denom = ex0;
    float acc = ex0 * __half2float(h1[(size_t)n * 64 + l]);
    int e = row_start[n], end = row_start[n + 1];
    int batched = e + ((end - e) & ~7);
    for (; e < batched; e += 8) {
        int sj = csr[e + j];                     // edge (l&7)'s src
        float aj = as[sj * 8 + h];               // (edge j, head h)
        float t = aj + adv;
        t = fmaxf(t, NEG_SLOPE * t);
        float xj = __expf(t);                    // one exp per (edge,head) pair
#pragma unroll
        for (int q = 0; q < 8; ++q) {
            int sq = __shfl(sj, q, 64);          // wave-uniform src of edge q
            float xq = __shfl(xj, lbase + q, 64);// exp(edge q, my head)
            float v = __half2float(h1[(size_t)sq * 64 + l]);
            denom += xq;
            acc = fmaf(xq, v, acc);
        }
    }
    for (; e < end; ++e) {
        int s0 = csr[e];
        float t = as[s0 * 8 + h] + adv;
        t = fmaxf(t, NEG_SLOPE * t);
        float x0 = __expf(t);
        denom += x0;
        acc = fmaf(x0, __half2float(h1[(size_t)s0 * 64 + l]), acc);
    }
    float v = acc / denom + b1[l];
    h1o[(size_t)n * 64 + l] = __float2half(v > 0.f ? v : expm1f(v));  // ELU
}

// ---------------- layer 2 aggregation: one wave per dst node, half2 lanes ---------
// lane l -> (head = l>>3, cpair = l&7 -> channels 2*cpair, 2*cpair+1); h2 fp16.
// Same 8-edge batched-exp structure as aggregate1_k.

__global__ __launch_bounds__(64) void aggregate2_k(
    const __half* __restrict__ h2, const float* __restrict__ as,
    const float* __restrict__ ad, const int* __restrict__ row_start,
    const int* __restrict__ csr, const float* __restrict__ b2,
    float* __restrict__ out, int N) {
    int n = blockIdx.x;
    int l = threadIdx.x;
    int h = l >> 3;
    int j = l & 7;
    int lbase = l & 56;
    const __half2* H = (const __half2*)h2;  // [n][64] half2
    float adv = ad[n * 8 + h];
    float e0 = as[n * 8 + h] + adv;
    e0 = fmaxf(e0, NEG_SLOPE * e0);
    float ex0 = __expf(e0);
    float denom = ex0;
    float2 self = __half22float2(H[(size_t)n * 64 + l]);
    float accx = ex0 * self.x, accy = ex0 * self.y;
    int e = row_start[n], end = row_start[n + 1];
    int batched = e + ((end - e) & ~7);
    for (; e < batched; e += 8) {
        int sj = csr[e + j];
        float aj = as[sj * 8 + h];
        float t = aj + adv;
        t = fmaxf(t, NEG_SLOPE * t);
        float xj = __expf(t);
#pragma unroll
        for (int q = 0; q < 8; ++q) {
            int sq = __shfl(sj, q, 64);
            float xq = __shfl(xj, lbase + q, 64);
            float2 v = __half22float2(H[(size_t)sq * 64 + l]);
            denom += xq;
            accx = fmaf(xq, v.x, accx);
            accy = fmaf(xq, v.y, accy);
        }
    }
    for (; e < end; ++e) {
        int s0 = csr[e];
        float t = as[s0 * 8 + h] + adv;
        t = fmaxf(t, NEG_SLOPE * t);
        float x0 = __expf(t);
        float2 v = __half22float2(H[(size_t)s0 * 64 + l]);
        denom += x0;
        accx = fmaf(x0, v.x, accx);
        accy = fmaf(x0, v.y, accy);
    }
    float rx = accx / denom, ry = accy / denom;
#pragma unroll
    for (int m = 8; m <= 32; m <<= 1) {
        rx += __shfl_xor(rx, m, 64);
        ry += __shfl_xor(ry, m, 64);
    }
    if (l < 8) {
        int c0 = l * 2;
        float2 o;
        o.x = rx * 0.125f + b2[c0];
        o.y = ry * 0.125f + b2[c0 + 1];
        *(float2*)(out + (size_t)n * 16 + c0) = o;
    }
}

// ---------------- launch ----------------

extern "C" void kernel_launch(void* const* d_in, const int* in_sizes, int n_in,
                              void* d_out, int out_size, void* d_ws, size_t ws_size,
                              hipStream_t stream) {
    (void)n_in; (void)out_size; (void)ws_size;
    const float* x      = (const float*)d_in[0];
    const int*   ei     = (const int*)d_in[1];
    const float* W1     = (const float*)d_in[2];
    const float* a_src1 = (const float*)d_in[3];
    const float* a_dst1 = (const float*)d_in[4];
    const float* b1     = (const float*)d_in[5];
    const float* W2     = (const float*)d_in[6];
    const float* a_src2 = (const float*)d_in[7];
    const float* a_dst2 = (const float*)d_in[8];
    const float* b2     = (const float*)d_in[9];

    int N = in_sizes[0] / 512;
    int E = in_sizes[1] / 2;
    const int* src = ei;
    const int* dst = ei + E;
    int NB = (N + 511) >> 9;  // 196 for N=100000; LDS arrays assume <= 256

    char* ws = (char*)d_ws;
    size_t off = 0;
    auto alloc = [&](size_t bytes) -> void* {
        void* p = ws + off;
        off = (off + bytes + 255) & ~(size_t)255;
        return p;
    };
    __half* h1  = (__half*)alloc((size_t)N * 64 * 2);
    __half* h1o = (__half*)alloc((size_t)N * 64 * 2);
    __half* h2  = (__half*)alloc((size_t)N * 128 * 2);
    float* as1  = (float*)alloc((size_t)N * 8 * 4);
    float* ad1  = (float*)alloc((size_t)N * 8 * 4);
    float* as2  = (float*)alloc((size_t)N * 8 * 4);
    float* ad2  = (float*)alloc((size_t)N * 8 * 4);
    _Float16* W1T = (_Float16*)alloc((size_t)512 * 64 * 2);
    _Float16* W2T = (_Float16*)alloc((size_t)64 * 128 * 2);
    int* row_start = (int*)alloc((size_t)(N + 1) * 4);
    int* bhist     = (int*)alloc(256 * 4);
    int* bbase     = (int*)alloc(257 * 4);
    int* cursor    = (int*)alloc(256 * 4);
    unsigned int* part = (unsigned int*)alloc((size_t)E * 4);
    int* csr       = (int*)alloc((size_t)E * 4);

    // --- weight transpose+convert (tiny, L2-resident thereafter) ---
    convw_k<<<(512 * 64 + 255) / 256, 256, 0, stream>>>(W1, W1T, 512, 64);
    convw_k<<<(64 * 128 + 255) / 256, 256, 0, stream>>>(W2, W2T, 64, 128);

    // --- bucketed CSR build (shared by both layers; self-loops folded analytically) ---
    hipMemsetAsync(bhist, 0, 256 * 4, stream);
    bucket_hist_k<<<512, 256, 0, stream>>>(dst, E, bhist, NB);
    bucket_scan_k<<<1, 256, 0, stream>>>(bhist, NB, bbase, cursor, row_start, N, E);
    partition_k<<<512, 256, 0, stream>>>(src, dst, E, cursor, part, NB);
    bucket_build_k<<<NB, 512, 0, stream>>>(part, bbase, row_start, csr, N);

    int gblocks = (N + 63) / 64;

    // --- layer 1 ---
    mfma_gemm_k<4, 512, true><<<gblocks, 256, 0, stream>>>(x, W1T, h1, N);
    alpha_k<8><<<(N * 8 + 255) / 256, 256, 0, stream>>>(h1, a_src1, a_dst1, as1, ad1, N * 8);
    aggregate1_k<<<N, 64, 0, stream>>>(h1, as1, ad1, row_start, csr, b1, h1o, N);

    // --- layer 2 ---
    mfma_gemm_k<8, 64, false><<<gblocks, 256, 0, stream>>>(h1o, W2T, h2, N);
    alpha_k<16><<<(N * 8 + 255) / 256, 256, 0, stream>>>(h2, a_src2, a_dst2, as2, ad2, N * 8);
    aggregate2_k<<<N, 64, 0, stream>>>(h2, as2, ad2, row_start, csr, b2, (float*)d_out, N);
}

// Round 7
// 653.570 us; speedup vs baseline: 2.0157x; 1.0644x over previous
//
#include <hip/hip_runtime.h>
#include <hip/hip_bf16.h>
#include <hip/hip_fp16.h>
#include <cstddef>

#define NEG_SLOPE 0.2f

typedef _Float16 half8 __attribute__((ext_vector_type(8)));
typedef float floatx4 __attribute__((ext_vector_type(4)));
typedef float floatx2 __attribute__((ext_vector_type(2)));

// ================= bucketed CSR build =================
// Bucket = 512 consecutive dst nodes. NB = ceil(N/512) (== 196 for N=100000, must be <= 256).
// part[] holds (src << 9) | (dst & 511) packed per edge, grouped by bucket.

__global__ __launch_bounds__(256) void bucket_hist_k(const int* __restrict__ dst, int E,
                                                     int* __restrict__ bhist, int NB) {
    __shared__ int lh[256];
    for (int t = threadIdx.x; t < 256; t += 256) lh[t] = 0;
    __syncthreads();
    int per = (E + gridDim.x - 1) / gridDim.x;
    int s = blockIdx.x * per;
    int e = min(s + per, E);
    for (int i = s + threadIdx.x; i < e; i += 256) atomicAdd(&lh[dst[i] >> 9], 1);
    __syncthreads();
    for (int t = threadIdx.x; t < NB; t += 256)
        if (lh[t]) atomicAdd(&bhist[t], lh[t]);
}

__global__ __launch_bounds__(256) void bucket_scan_k(const int* __restrict__ bhist, int NB,
                                                     int* __restrict__ bbase, int* __restrict__ cursor,
                                                     int* __restrict__ row_start, int N, int E) {
    __shared__ int tmp[256];
    int tid = threadIdx.x;
    int v = (tid < NB) ? bhist[tid] : 0;
    tmp[tid] = v;
    __syncthreads();
    for (int d = 1; d < 256; d <<= 1) {
        int t = tmp[tid];
        int a = (tid >= d) ? tmp[tid - d] : 0;
        __syncthreads();
        tmp[tid] = t + a;
        __syncthreads();
    }
    if (tid < NB) {
        int b = tmp[tid] - v;  // exclusive
        bbase[tid] = b;
        cursor[tid] = b;
    }
    if (tid == 0) {
        bbase[NB] = E;
        row_start[N] = E;
    }
}

__global__ __launch_bounds__(256) void partition_k(const int* __restrict__ src,
                                                   const int* __restrict__ dst, int E,
                                                   int* __restrict__ cursor,
                                                   unsigned int* __restrict__ part, int NB) {
    __shared__ int lh[256];
    __shared__ int lbase[256];
    for (int t = threadIdx.x; t < 256; t += 256) lh[t] = 0;
    __syncthreads();
    int per = (E + gridDim.x - 1) / gridDim.x;
    int s = blockIdx.x * per;
    int e = min(s + per, E);
    for (int i = s + threadIdx.x; i < e; i += 256) atomicAdd(&lh[dst[i] >> 9], 1);
    __syncthreads();
    for (int t = threadIdx.x; t < NB; t += 256) {
        int c = lh[t];
        lbase[t] = c ? atomicAdd(&cursor[t], c) : 0;
        lh[t] = 0;  // becomes local cursor
    }
    __syncthreads();
    for (int i = s + threadIdx.x; i < e; i += 256) {
        int d = dst[i];
        int b = d >> 9;
        int lo = atomicAdd(&lh[b], 1);
        part[lbase[b] + lo] = ((unsigned)src[i] << 9) | (unsigned)(d & 511);
    }
}

// One workgroup per bucket: per-node counts + scan in LDS -> row_start; then scatter
// src ids into the bucket's contiguous csr window (L2-resident, ~64 KB).
// (R5's per-node src-chunk sort was measured neutral -- reverted.)
__global__ __launch_bounds__(512) void bucket_build_k(const unsigned int* __restrict__ part,
                                                      const int* __restrict__ bbase,
                                                      int* __restrict__ row_start,
                                                      int* __restrict__ csr, int N) {
    __shared__ int cnt[512];
    __shared__ int cur[512];
    int b = blockIdx.x, tid = threadIdx.x;
    int n0 = b << 9;
    int s = bbase[b], e2 = bbase[b + 1];
    cnt[tid] = 0;
    __syncthreads();
    for (int i = s + tid; i < e2; i += 512) atomicAdd(&cnt[part[i] & 511], 1);
    __syncthreads();
    int v = cnt[tid];
    for (int d = 1; d < 512; d <<= 1) {  // inclusive scan, in place
        int t = cnt[tid];
        int a = (tid >= d) ? cnt[tid - d] : 0;
        __syncthreads();
        cnt[tid] = t + a;
        __syncthreads();
    }
    int excl = cnt[tid] - v;
    if (n0 + tid < N) row_start[n0 + tid] = s + excl;
    cur[tid] = excl;
    __syncthreads();
    for (int i = s + tid; i < e2; i += 512) {
        unsigned u = part[i];
        int p = atomicAdd(&cur[u & 511], 1);
        csr[s + p] = (int)(u >> 9);
    }
}

// ---------------- W transpose+convert: W [K][Nc] fp32 -> WT [Nc][K] f16 ----------------

__global__ void convw_k(const float* __restrict__ W, _Float16* __restrict__ WT,
                        int K, int Nc) {
    int i = blockIdx.x * 256 + threadIdx.x;
    if (i < K * Nc) {
        int k = i / Nc, n = i % Nc;
        WT[(size_t)n * K + k] = (_Float16)W[i];
    }
}

// ---------------- fp16 -> fp8 e4m3 (OCP) pairwise convert ----------------

__global__ void convf8_k(const __half2* __restrict__ in, unsigned short* __restrict__ out,
                         int n2) {
    int i = blockIdx.x * 256 + threadIdx.x;
    if (i < n2) {
        float2 f = __half22float2(in[i]);
        int p = __builtin_amdgcn_cvt_pk_fp8_f32(f.x, f.y, 0, false);
        out[i] = (unsigned short)(p & 0xffff);
    }
}

// ---------------- MFMA f16 GEMM: C[M,Nc] = A[M,K] @ BT[Nc,K]^T, fp32 accumulate ----
// Block = 4 waves x 16 M-rows = 64 rows; N covered fully (NT = Nc/16 tiles per wave).
// A loaded straight from global per fragment (fp32 variant converts inline);
// BT is f16 [Nc][K] (L2-resident, <=64 KB). No LDS.
// Fragment layouts (m89/m120-verified): A[m=lane&15][k=quad*8+j];
// B[k=quad*8+j][n=lane&15]; C/D col=lane&15, row=quad*4+reg.

template <int NT, int K, bool AF32>
__global__ __launch_bounds__(256) void mfma_gemm_k(const void* __restrict__ Av,
                                                   const _Float16* __restrict__ BT,
                                                   __half* __restrict__ C, int M) {
    constexpr int Nc = NT * 16;
    int wave = threadIdx.x >> 6, lane = threadIdx.x & 63;
    int m16 = lane & 15, quad = lane >> 4;
    int arow = blockIdx.x * 64 + wave * 16 + m16;
    int arc = arow < M ? arow : M - 1;  // clamp: OOB rows compute garbage, never stored
    floatx4 acc[NT] = {};
    for (int k0 = 0; k0 < K; k0 += 32) {
        half8 af;
        if constexpr (AF32) {
            const float* ap = (const float*)Av + (size_t)arc * K + k0 + quad * 8;
            float4 v0 = *(const float4*)ap;
            float4 v1 = *(const float4*)(ap + 4);
            af[0] = (_Float16)v0.x; af[1] = (_Float16)v0.y;
            af[2] = (_Float16)v0.z; af[3] = (_Float16)v0.w;
            af[4] = (_Float16)v1.x; af[5] = (_Float16)v1.y;
            af[6] = (_Float16)v1.z; af[7] = (_Float16)v1.w;
        } else {
            af = *(const half8*)((const _Float16*)Av + (size_t)arc * K + k0 + quad * 8);
        }
#pragma unroll
        for (int t = 0; t < NT; ++t) {
            half8 bf = *(const half8*)(BT + (size_t)(t * 16 + m16) * K + k0 + quad * 8);
            acc[t] = __builtin_amdgcn_mfma_f32_16x16x32_f16(af, bf, acc[t], 0, 0, 0);
        }
    }
    int gm0 = blockIdx.x * 64 + wave * 16 + quad * 4;
#pragma unroll
    for (int t = 0; t < NT; ++t)
#pragma unroll
        for (int r = 0; r < 4; ++r) {
            int gm = gm0 + r;
            if (gm < M) C[(size_t)gm * Nc + t * 16 + m16] = __float2half(acc[t][r]);
        }
}

// ---------------- attention scores: alpha_s/alpha_d per (node, head) ----------------

template <int C>
__global__ void alpha_k(const __half* __restrict__ h, const float* __restrict__ a_s,
                        const float* __restrict__ a_d, float* __restrict__ os,
                        float* __restrict__ od, int NH) {
    int i = blockIdx.x * 256 + threadIdx.x;  // i = n*8 + head
    if (i >= NH) return;
    int hh = i & 7;
    const __half* hp = h + (size_t)i * C;
    float s = 0.f, d = 0.f;
#pragma unroll
    for (int c = 0; c < C; ++c) {
        float v = __half2float(hp[c]);
        s = fmaf(v, a_s[hh * C + c], s);
        d = fmaf(v, a_d[hh * C + c], d);
    }
    os[i] = s;
    od[i] = d;
}

// ---------------- layer 1 aggregation: one 64-lane wave per dst node ----------------
// lane l -> (head = l>>3, ch = l&7); h1 layout [n][h*8+c] = [n][l], fp16.
// 8-edge batches: phase A lane l computes exp for (edge l&7, head l>>3) -- one
// v_exp_f32 covers 8 edges x 8 heads; phase B broadcasts via readlane/bpermute.

__global__ __launch_bounds__(64) void aggregate1_k(
    const __half* __restrict__ h1, const float* __restrict__ as,
    const float* __restrict__ ad, const int* __restrict__ row_start,
    const int* __restrict__ csr, const float* __restrict__ b1,
    __half* __restrict__ h1o, int N) {
    int n = blockIdx.x;
    int l = threadIdx.x;
    int h = l >> 3;
    int j = l & 7;
    int lbase = l & 56;
    float adv = ad[n * 8 + h];
    float e0 = as[n * 8 + h] + adv;
    e0 = fmaxf(e0, NEG_SLOPE * e0);
    float ex0 = __expf(e0);
    float denom = ex0;
    float acc = ex0 * __half2float(h1[(size_t)n * 64 + l]);
    int e = row_start[n], end = row_start[n + 1];
    int batched = e + ((end - e) & ~7);
    for (; e < batched; e += 8) {
        int sj = csr[e + j];                     // edge (l&7)'s src
        float aj = as[sj * 8 + h];               // (edge j, head h)
        float t = aj + adv;
        t = fmaxf(t, NEG_SLOPE * t);
        float xj = __expf(t);                    // one exp per (edge,head) pair
#pragma unroll
        for (int q = 0; q < 8; ++q) {
            int sq = __shfl(sj, q, 64);          // wave-uniform src of edge q
            float xq = __shfl(xj, lbase + q, 64);// exp(edge q, my head)
            float v = __half2float(h1[(size_t)sq * 64 + l]);
            denom += xq;
            acc = fmaf(xq, v, acc);
        }
    }
    for (; e < end; ++e) {
        int s0 = csr[e];
        float t = as[s0 * 8 + h] + adv;
        t = fmaxf(t, NEG_SLOPE * t);
        float x0 = __expf(t);
        denom += x0;
        acc = fmaf(x0, __half2float(h1[(size_t)s0 * 64 + l]), acc);
    }
    float v = acc / denom + b1[l];
    h1o[(size_t)n * 64 + l] = __float2half(v > 0.f ? v : expm1f(v));  // ELU
}

// ---------------- layer 2 aggregation: one wave per dst node, fp8 gathers ---------
// lane l -> (head = l>>3, cpair = l&7 -> channels 2*cpair, 2*cpair+1).
// h2f8 row = 128 bytes; lane l reads the uchar2 at byte offset l*2 -> one
// fully-coalesced 128 B load per edge (2 cache lines instead of 4 with fp16).

__global__ __launch_bounds__(64) void aggregate2_k(
    const unsigned short* __restrict__ h2f8, const float* __restrict__ as,
    const float* __restrict__ ad, const int* __restrict__ row_start,
    const int* __restrict__ csr, const float* __restrict__ b2,
    float* __restrict__ out, int N) {
    int n = blockIdx.x;
    int l = threadIdx.x;
    int h = l >> 3;
    int j = l & 7;
    int lbase = l & 56;
    float adv = ad[n * 8 + h];
    float e0 = as[n * 8 + h] + adv;
    e0 = fmaxf(e0, NEG_SLOPE * e0);
    float ex0 = __expf(e0);
    float denom = ex0;
    floatx2 self = __builtin_amdgcn_cvt_pk_f32_fp8((int)h2f8[(size_t)n * 64 + l], false);
    float accx = ex0 * self[0], accy = ex0 * self[1];
    int e = row_start[n], end = row_start[n + 1];
    int batched = e + ((end - e) & ~7);
    for (; e < batched; e += 8) {
        int sj = csr[e + j];
        float aj = as[sj * 8 + h];
        float t = aj + adv;
        t = fmaxf(t, NEG_SLOPE * t);
        float xj = __expf(t);
#pragma unroll
        for (int q = 0; q < 8; ++q) {
            int sq = __shfl(sj, q, 64);
            float xq = __shfl(xj, lbase + q, 64);
            floatx2 v = __builtin_amdgcn_cvt_pk_f32_fp8((int)h2f8[(size_t)sq * 64 + l], false);
            denom += xq;
            accx = fmaf(xq, v[0], accx);
            accy = fmaf(xq, v[1], accy);
        }
    }
    for (; e < end; ++e) {
        int s0 = csr[e];
        float t = as[s0 * 8 + h] + adv;
        t = fmaxf(t, NEG_SLOPE * t);
        float x0 = __expf(t);
        floatx2 v = __builtin_amdgcn_cvt_pk_f32_fp8((int)h2f8[(size_t)s0 * 64 + l], false);
        denom += x0;
        accx = fmaf(x0, v[0], accx);
        accy = fmaf(x0, v[1], accy);
    }
    float rx = accx / denom, ry = accy / denom;
#pragma unroll
    for (int m = 8; m <= 32; m <<= 1) {
        rx += __shfl_xor(rx, m, 64);
        ry += __shfl_xor(ry, m, 64);
    }
    if (l < 8) {
        int c0 = l * 2;
        float2 o;
        o.x = rx * 0.125f + b2[c0];
        o.y = ry * 0.125f + b2[c0 + 1];
        *(float2*)(out + (size_t)n * 16 + c0) = o;
    }
}

// ---------------- launch ----------------

extern "C" void kernel_launch(void* const* d_in, const int* in_sizes, int n_in,
                              void* d_out, int out_size, void* d_ws, size_t ws_size,
                              hipStream_t stream) {
    (void)n_in; (void)out_size; (void)ws_size;
    const float* x      = (const float*)d_in[0];
    const int*   ei     = (const int*)d_in[1];
    const float* W1     = (const float*)d_in[2];
    const float* a_src1 = (const float*)d_in[3];
    const float* a_dst1 = (const float*)d_in[4];
    const float* b1     = (const float*)d_in[5];
    const float* W2     = (const float*)d_in[6];
    const float* a_src2 = (const float*)d_in[7];
    const float* a_dst2 = (const float*)d_in[8];
    const float* b2     = (const float*)d_in[9];

    int N = in_sizes[0] / 512;
    int E = in_sizes[1] / 2;
    const int* src = ei;
    const int* dst = ei + E;
    int NB = (N + 511) >> 9;  // 196 for N=100000; LDS arrays assume <= 256

    char* ws = (char*)d_ws;
    size_t off = 0;
    auto alloc = [&](size_t bytes) -> void* {
        void* p = ws + off;
        off = (off + bytes + 255) & ~(size_t)255;
        return p;
    };
    __half* h1  = (__half*)alloc((size_t)N * 64 * 2);
    __half* h1o = (__half*)alloc((size_t)N * 64 * 2);
    __half* h2  = (__half*)alloc((size_t)N * 128 * 2);
    unsigned short* h2f8 = (unsigned short*)alloc((size_t)N * 64 * 2);  // fp8 pairs
    float* as1  = (float*)alloc((size_t)N * 8 * 4);
    float* ad1  = (float*)alloc((size_t)N * 8 * 4);
    float* as2  = (float*)alloc((size_t)N * 8 * 4);
    float* ad2  = (float*)alloc((size_t)N * 8 * 4);
    _Float16* W1T = (_Float16*)alloc((size_t)512 * 64 * 2);
    _Float16* W2T = (_Float16*)alloc((size_t)64 * 128 * 2);
    int* row_start = (int*)alloc((size_t)(N + 1) * 4);
    int* bhist     = (int*)alloc(256 * 4);
    int* bbase     = (int*)alloc(257 * 4);
    int* cursor    = (int*)alloc(256 * 4);
    unsigned int* part = (unsigned int*)alloc((size_t)E * 4);
    int* csr       = (int*)alloc((size_t)E * 4);

    // --- weight transpose+convert (tiny, L2-resident thereafter) ---
    convw_k<<<(512 * 64 + 255) / 256, 256, 0, stream>>>(W1, W1T, 512, 64);
    convw_k<<<(64 * 128 + 255) / 256, 256, 0, stream>>>(W2, W2T, 64, 128);

    // --- bucketed CSR build (shared by both layers; self-loops folded analytically) ---
    hipMemsetAsync(bhist, 0, 256 * 4, stream);
    bucket_hist_k<<<512, 256, 0, stream>>>(dst, E, bhist, NB);
    bucket_scan_k<<<1, 256, 0, stream>>>(bhist, NB, bbase, cursor, row_start, N, E);
    partition_k<<<512, 256, 0, stream>>>(src, dst, E, cursor, part, NB);
    bucket_build_k<<<NB, 512, 0, stream>>>(part, bbase, row_start, csr, N);

    int gblocks = (N + 63) / 64;

    // --- layer 1 ---
    mfma_gemm_k<4, 512, true><<<gblocks, 256, 0, stream>>>(x, W1T, h1, N);
    alpha_k<8><<<(N * 8 + 255) / 256, 256, 0, stream>>>(h1, a_src1, a_dst1, as1, ad1, N * 8);
    aggregate1_k<<<N, 64, 0, stream>>>(h1, as1, ad1, row_start, csr, b1, h1o, N);

    // --- layer 2 ---
    mfma_gemm_k<8, 64, false><<<gblocks, 256, 0, stream>>>(h1o, W2T, h2, N);
    convf8_k<<<(N * 64 + 255) / 256, 256, 0, stream>>>((const __half2*)h2, h2f8, N * 64);
    alpha_k<16><<<(N * 8 + 255) / 256, 256, 0, stream>>>(h2, a_src2, a_dst2, as2, ad2, N * 8);
    aggregate2_k<<<N, 64, 0, stream>>>(h2f8, as2, ad2, row_start, csr, b2, (float*)d_out, N);
}